// Round 4
// baseline (596.118 us; speedup 1.0000x reference)
//
#include <hip/hip_runtime.h>
#include <cstdint>
#include <cstddef>

// ---------------- problem constants ----------------
#define L_SEQ   4096
#define DIM_IN  1024
#define DI      1536
#define BATCH   4

typedef unsigned short u16;
typedef __attribute__((ext_vector_type(8))) short  short8;   // 8 bf16 = 4 VGPRs
typedef __attribute__((ext_vector_type(4))) float  f32x4;

struct __align__(8) u16x4 { u16 x, y, z, w; };

// ---------------- helpers ----------------
__device__ __forceinline__ float bf2f(u16 u) {
  union { unsigned int i; float f; } v; v.i = ((unsigned int)u) << 16; return v.f;
}
__device__ __forceinline__ u16 f2bf(float f) {
  union { float f; unsigned int i; } v; v.f = f;
  unsigned int x = v.i;
  return (u16)((x + 0x7fffu + ((x >> 16) & 1u)) >> 16);   // RNE
}
__device__ __forceinline__ float siluf_(float v) {
  return v / (1.0f + __expf(-v));
}
__device__ __forceinline__ float softplusf_(float v) {
  return fmaxf(v, 0.0f) + log1pf(__expf(-fabsf(v)));
}
__device__ __forceinline__ void gload16(const void* g, void* l) {
  __builtin_amdgcn_global_load_lds((const __attribute__((address_space(1))) void*)g,
                                   (__attribute__((address_space(3))) void*)l,
                                   16, 0, 0);
}
// LDS byte offset of a generic pointer into __shared__
__device__ __forceinline__ unsigned lds_off(const void* p) {
  return (unsigned)(uintptr_t)(const __attribute__((address_space(3))) void*)p;
}
// inline-asm ds_read_b128: invisible to the waitcnt pass. MUST pair with
// s_waitcnt lgkmcnt(0) + sched_barrier(0) before consuming (rule #18).
__device__ __forceinline__ short8 dsread128(unsigned off) {
  short8 r;
  asm volatile("ds_read_b128 %0, %1" : "=v"(r) : "v"(off));
  return r;
}
// raw barrier, invisible to compiler passes that special-case S_BARRIER
// (hypothesis from r1/r2: compiler-visible barriers get a vmcnt(0) flush,
// which converts the counted-vmcnt 8-phase into drain-per-phase).
#define RAW_BARRIER() asm volatile("s_barrier" ::: "memory")

// ---------------- fp32 -> bf16 convert ----------------
__global__ void to_bf16(const float* __restrict__ in, u16* __restrict__ out, int n4) {
  int i = blockIdx.x * blockDim.x + threadIdx.x;
  if (i >= n4) return;
  float4 v = ((const float4*)in)[i];
  u16x4 o;
  o.x = f2bf(v.x); o.y = f2bf(v.y); o.z = f2bf(v.z); o.w = f2bf(v.w);
  ((u16x4*)out)[i] = o;
}

// ================= EXPERIMENT: 256x256 8-phase GEMM (in_proj only) =============
// BM=BN=256, BK=64, 8 waves (4M x 2N), per-wave 64x128, 128 KiB LDS dbuf,
// both-sides XOR swizzle, counted vmcnt (never 0 mid-loop), asm ds_read,
// RAW asm barriers, predicated tail stages with vmcnt(6)->vmcnt(0) switch.
//
// vmcnt ledger (2 vmem ops per STAGE_*):
//   prologue: tile0 (8) + tile1 A0,A1,B0 (6) -> vmcnt(6) = tile0 landed, 6 in flight.
//   iter t (t+2<NT): P0 +B1(t+1)->8; P1 +A0(t+2)->10; P2 +A1(t+2)->12;
//     P3 +B0(t+2)->14; vmcnt(6) drains 8 oldest = tile t+1 complete. 6 remain.
//   t==NT-2: P1..P3 stages skipped -> 8 outstanding at P3 -> vmcnt(0).
//   t==NT-1: nothing staged; vmcnt(0) trivial.
__device__ __forceinline__ void mma_ph8(f32x4 (&acc)[4][8], const short8 (&a)[4][2],
                                        const short8 (&b)[2][2], int p) {
#pragma unroll
  for (int kb = 0; kb < 2; ++kb)
#pragma unroll
    for (int i = 0; i < 4; ++i)
#pragma unroll
      for (int n = 0; n < 2; ++n)
        acc[i][p * 2 + n] = __builtin_amdgcn_mfma_f32_16x16x32_bf16(a[i][kb], b[n][kb],
                                                                    acc[i][p * 2 + n], 0, 0, 0);
}

// EPI 1 only (in_proj): col<DI -> bf16 e_bf_a ; col>=DI -> silu -> bf16 e_bf1
__launch_bounds__(512, 2)
__global__ void gemm256(const u16* __restrict__ A, const u16* __restrict__ Bt,
                        int N, int K,
                        u16* __restrict__ e_bf_a,
                        u16* __restrict__ e_bf1) {
  __shared__ u16 smem[2][2][256 * 64];   // 128 KiB: [dbuf][A|B][256r][64c]

  const int tid  = threadIdx.x;          // 0..511
  const int wave = tid >> 6;             // 0..7
  const int lane = tid & 63;
  const int quad = lane >> 4;
  const int l16  = lane & 15;
  const int waveM = wave & 3;
  const int waveN = wave >> 2;
  const int xorc  = (l16 & 7) << 3;

  // bijective XCD swizzle (nwg % 8 == 0 here)
  const int nwg  = (int)(gridDim.x * gridDim.y);
  const int orig = (int)(blockIdx.y * gridDim.x + blockIdx.x);
  const int swz  = (orig & 7) * (nwg >> 3) + (orig >> 3);
  const int bx   = swz % (int)gridDim.x;
  const int by   = swz / (int)gridDim.x;
  const int m0 = by * 256;
  const int n0 = bx * 256;
  const int NT = K >> 6;

  const int srow = tid >> 3;
  const int scol = ((tid & 7) ^ (srow & 7)) * 8;
  const u16* gA = A  + (size_t)(m0 + srow) * K + scol;
  const u16* gB = Bt + (size_t)(n0 + srow) * K + scol;

#define STAGE2(gptr, mat, kk, r0, r1) do {                                      \
    const u16* _s0 = gptr + (size_t)(r0) * K + (size_t)(kk) * 64;               \
    const u16* _s1 = gptr + (size_t)(r1) * K + (size_t)(kk) * 64;               \
    gload16(_s0, &smem[(kk) & 1][mat][((r0) + wave * 8) * 64]);                 \
    gload16(_s1, &smem[(kk) & 1][mat][((r1) + wave * 8) * 64]);                 \
  } while (0)
#define STAGE_A(kk, h) STAGE2(gA, 0, kk, (h) * 128, (h) * 128 + 64)
#define STAGE_B(kk, h) STAGE2(gB, 1, kk, (h) * 64, (h) * 64 + 128)

  STAGE_A(0, 0); STAGE_A(0, 1); STAGE_B(0, 0); STAGE_B(0, 1);
  if (NT > 1) { STAGE_A(1, 0); STAGE_A(1, 1); STAGE_B(1, 0); }
  if (NT > 1) asm volatile("s_waitcnt vmcnt(6)" ::: "memory");
  else        asm volatile("s_waitcnt vmcnt(0)" ::: "memory");
  RAW_BARRIER();

  f32x4 acc[4][8] = {};
  short8 a[4][2], b[2][2];

  const unsigned ldsBase = lds_off(&smem[0][0][0]);
  const unsigned rowA = (unsigned)(waveM * 64 + l16) * 128u;
  const unsigned rowB = (unsigned)(waveN * 128 + l16) * 128u;
  const unsigned ck0  = (unsigned)(((0 * 32 + quad * 8) ^ xorc) * 2);
  const unsigned ck1  = (unsigned)(((1 * 32 + quad * 8) ^ xorc) * 2);

#define LDB8(Bc, p) do {                                                        \
    const unsigned _rb = (Bc) + rowB + (unsigned)(p) * 4096u;                   \
    b[0][0] = dsread128(_rb + ck0);                                             \
    b[0][1] = dsread128(_rb + ck1);                                             \
    b[1][0] = dsread128(_rb + 2048u + ck0);                                     \
    b[1][1] = dsread128(_rb + 2048u + ck1);                                     \
  } while (0)
#define WAIT_LGKM() do {                                                        \
    asm volatile("s_waitcnt lgkmcnt(0)" ::: "memory");                          \
    __builtin_amdgcn_sched_barrier(0);                                          \
  } while (0)
#define PH_TAIL(p) do {                                                         \
    RAW_BARRIER();                                                              \
    WAIT_LGKM();                                                                \
    __builtin_amdgcn_s_setprio(1);                                              \
    mma_ph8(acc, a, b, p);                                                      \
    __builtin_amdgcn_s_setprio(0);                                              \
    RAW_BARRIER();                                                              \
  } while (0)

  for (int t = 0; t < NT; ++t) {
    const int cur = t & 1;
    const bool s1 = (t + 1 < NT);
    const bool s2 = (t + 2 < NT);
    const unsigned Ac = ldsBase + (unsigned)cur * 65536u;
    const unsigned Bc = Ac + 32768u;

    // ---- phase 0: ds_read A(all) + B p=0 ; stage B1(t+1) ; MFMA p=0
#pragma unroll
    for (int i = 0; i < 4; ++i) {
      const unsigned ra = Ac + rowA + (unsigned)i * 2048u;
      a[i][0] = dsread128(ra + ck0);
      a[i][1] = dsread128(ra + ck1);
    }
    LDB8(Bc, 0);
    if (s1) STAGE_B(t + 1, 1);
    PH_TAIL(0);

    // ---- phase 1: B p=1 ; stage A0(t+2) ; MFMA p=1
    LDB8(Bc, 1);
    if (s2) STAGE_A(t + 2, 0);
    PH_TAIL(1);

    // ---- phase 2: B p=2 ; stage A1(t+2) ; MFMA p=2
    LDB8(Bc, 2);
    if (s2) STAGE_A(t + 2, 1);
    PH_TAIL(2);

    // ---- phase 3: B p=3 ; stage B0(t+2) ; counted vmcnt ; MFMA p=3
    LDB8(Bc, 3);
    if (s2) {
      STAGE_B(t + 2, 0);
      asm volatile("s_waitcnt vmcnt(6)" ::: "memory");
    } else {
      asm volatile("s_waitcnt vmcnt(0)" ::: "memory");
    }
    PH_TAIL(3);
  }
#undef STAGE_A
#undef STAGE_B
#undef STAGE2
#undef LDB8
#undef WAIT_LGKM
#undef PH_TAIL

  // epilogue (EPI1): C/D layout col=lane&15, row=quad*4+reg
#pragma unroll
  for (int mi = 0; mi < 4; ++mi) {
    const int rowBase = m0 + waveM * 64 + mi * 16 + quad * 4;
#pragma unroll
    for (int ni = 0; ni < 8; ++ni) {
      const int gcol = n0 + waveN * 128 + ni * 16 + l16;
#pragma unroll
      for (int r = 0; r < 4; ++r) {
        const float v = acc[mi][ni][r];
        const size_t row = (size_t)(rowBase + r);
        if (gcol < DI) e_bf_a[row * DI + gcol] = f2bf(v);
        else           e_bf1[row * DI + (gcol - DI)] = f2bf(siluf_(v));
      }
    }
  }
}

// ================= PROVEN: 128x128 2-barrier GEMM (r3, 701 TF) ================
// BK=64, both-sides swizzle, XCD swizzle. Used for dt + out_proj (+ fallback).
template <int EPI>
__launch_bounds__(256, 3)
__global__ void gemm_bt(const u16* __restrict__ A, const u16* __restrict__ Bt,
                        float* __restrict__ c_out,
                        int N, int K,
                        u16* __restrict__ e_bf_a,
                        u16* __restrict__ e_bf1,
                        const u16* __restrict__ e_bf2,
                        const float* __restrict__ e_v1,
                        const float* __restrict__ e_v2) {
  __shared__ u16 Alds[128 * 64];   // 16 KB
  __shared__ u16 Blds[128 * 64];   // 16 KB

  const int tid  = threadIdx.x;
  const int wave = tid >> 6;
  const int lane = tid & 63;
  const int quad = lane >> 4;
  const int l16  = lane & 15;

  const int nwg  = (int)(gridDim.x * gridDim.y);
  const int orig = (int)(blockIdx.y * gridDim.x + blockIdx.x);
  const int swz  = (orig & 7) * (nwg >> 3) + (orig >> 3);
  const int bx   = swz % (int)gridDim.x;
  const int by   = swz / (int)gridDim.x;
  const int m0 = by * 128;
  const int n0 = bx * 128;

  const int waveM = wave & 1;
  const int waveN = wave >> 1;

  const int srow = tid >> 3;                       // 0..31
  const int scol = ((tid & 7) ^ (srow & 7)) * 8;
  const u16* Ap = A  + (size_t)(m0 + srow) * K + scol;
  const u16* Bp = Bt + (size_t)(n0 + srow) * K + scol;
  u16* adst = &Alds[tid * 8];
  u16* bdst = &Blds[tid * 8];

  const unsigned xorc = (unsigned)(l16 & 7) << 3;

  f32x4 acc[4][4] = {};

  for (int k0 = 0; k0 < K; k0 += 64) {
#pragma unroll
    for (int r = 0; r < 4; ++r) {
      gload16(Ap + (size_t)(r * 32) * K + k0, adst + r * 2048);
      gload16(Bp + (size_t)(r * 32) * K + k0, bdst + r * 2048);
    }
    __syncthreads();

#pragma unroll
    for (int kb = 0; kb < 2; ++kb) {
      short8 af[4], bf[4];
      const unsigned ck = (unsigned)(kb * 32 + quad * 8) ^ xorc;
#pragma unroll
      for (int i = 0; i < 4; i++) {
        af[i] = *(const short8*)&Alds[(unsigned)(waveM * 64 + i * 16 + l16) * 64 + ck];
        bf[i] = *(const short8*)&Blds[(unsigned)(waveN * 64 + i * 16 + l16) * 64 + ck];
      }
#pragma unroll
      for (int mi = 0; mi < 4; mi++)
#pragma unroll
        for (int ni = 0; ni < 4; ni++)
          acc[mi][ni] = __builtin_amdgcn_mfma_f32_16x16x32_bf16(af[mi], bf[ni],
                                                                acc[mi][ni], 0, 0, 0);
    }
    __syncthreads();
  }

#pragma unroll
  for (int mi = 0; mi < 4; mi++) {
    const int rowBase = m0 + waveM * 64 + mi * 16 + quad * 4;
#pragma unroll
    for (int ni = 0; ni < 4; ni++) {
      const int gcol = n0 + waveN * 64 + ni * 16 + l16;
#pragma unroll
      for (int r = 0; r < 4; r++) {
        const float v = acc[mi][ni][r];
        const size_t row = (size_t)(rowBase + r);
        if constexpr (EPI == 0) {
          c_out[row * (size_t)N + gcol] = v;
        } else if constexpr (EPI == 1) {
          if (gcol < DI) {
            e_bf_a[row * DI + gcol] = f2bf(v);
          } else {
            e_bf1[row * DI + (gcol - DI)] = f2bf(siluf_(v));
          }
        } else {
          const float dt = softplusf_(v + e_v2[gcol]);
          const float a  = __expf(e_v1[gcol] * dt);
          const float xc = bf2f(e_bf2[row * DI + gcol]);
          e_bf_a[row * DI + gcol] = f2bf(xc * dt * a);
          e_bf1[row * DI + gcol] = f2bf(a);
        }
      }
    }
  }
}

// ---------------- depthwise conv1d(k=3,pad=1) + bias + SiLU ----------------------
__global__ void conv_silu(const u16* __restrict__ xin, const float* __restrict__ cw,
                          const float* __restrict__ cb, u16* __restrict__ xconv_bf) {
  const int idx = blockIdx.x * blockDim.x + threadIdx.x;   // one thread = 4 channels
  const int c4  = (idx % (DI / 4)) * 4;
  const int row = idx / (DI / 4);
  const int l   = row & (L_SEQ - 1);

  const size_t base = (size_t)row * DI + c4;
  u16x4 z4 = {0, 0, 0, 0};
  u16x4 x1 = *(const u16x4*)(xin + base);
  u16x4 x0 = (l > 0)         ? *(const u16x4*)(xin + base - DI) : z4;
  u16x4 x2 = (l < L_SEQ - 1) ? *(const u16x4*)(xin + base + DI) : z4;

  const u16* p0 = (const u16*)&x0;
  const u16* p1 = (const u16*)&x1;
  const u16* p2 = (const u16*)&x2;
  u16x4 o;
  u16* po = (u16*)&o;
#pragma unroll
  for (int j = 0; j < 4; j++) {
    const int c = c4 + j;
    float v = fmaf(cw[c * 3 + 0], bf2f(p0[j]),
              fmaf(cw[c * 3 + 1], bf2f(p1[j]),
                   cw[c * 3 + 2] * bf2f(p2[j]))) + cb[c];
    po[j] = f2bf(siluf_(v));
  }
  *(u16x4*)&xconv_bf[base] = o;
}

// ---------------- chunked prefix scan over L (chunk=128, 32 chunks/batch) --------
#define CHUNK 128
#define NCHUNK (L_SEQ / CHUNK)   // 32

__global__ void scan_partial(const u16* __restrict__ w, float* __restrict__ partial) {
  const int c  = blockIdx.x * 256 + threadIdx.x;   // 0..1535
  const int ch = blockIdx.y;
  const int b  = blockIdx.z;
  size_t base = ((size_t)b * L_SEQ + (size_t)ch * CHUNK) * DI + c;
  float s = 0.0f;
#pragma unroll 4
  for (int i = 0; i < CHUNK; i++) s += bf2f(w[base + (size_t)i * DI]);
  partial[((size_t)b * NCHUNK + ch) * DI + c] = s;
}

// scan_offsets folded in: each block sums partials of preceding chunks itself.
// NOTE: ybf aliases aexp (same index read-then-write per thread) — no __restrict__.
__global__ void scan_apply(const u16* __restrict__ w, const float* __restrict__ partial,
                           const u16* aexp, const u16* __restrict__ xconv,
                           const u16* __restrict__ sz, const float* __restrict__ Dp,
                           u16* ybf) {
  const int c  = blockIdx.x * 256 + threadIdx.x;
  const int ch = blockIdx.y;
  const int b  = blockIdx.z;
  float run = 0.0f;
  for (int j = 0; j < ch; ++j)
    run += partial[((size_t)b * NCHUNK + j) * DI + c];
  const float dp = Dp[c];
  size_t base = ((size_t)b * L_SEQ + (size_t)ch * CHUNK) * DI + c;
  for (int i = 0; i < CHUNK; i++) {
    size_t p = base + (size_t)i * DI;
    float ae = bf2f(aexp[p]);             // read BEFORE the aliased write
    run += bf2f(w[p]);
    float y = run * ae + bf2f(xconv[p]) * dp;
    y *= bf2f(sz[p]);
    ybf[p] = f2bf(y);
  }
}

// ---------------- launcher ----------------
extern "C" void kernel_launch(void* const* d_in, const int* in_sizes, int n_in,
                              void* d_out, int out_size, void* d_ws, size_t ws_size,
                              hipStream_t stream) {
  const float* x      = (const float*)d_in[0];
  const float* W_in   = (const float*)d_in[1];   // (3072,1024)
  const float* W_out  = (const float*)d_in[2];   // (1024,1536)
  const float* conv_w = (const float*)d_in[3];   // (1536,1,3)
  const float* conv_b = (const float*)d_in[4];
  const float* dt_w   = (const float*)d_in[5];   // (1536,1536)
  const float* dt_b   = (const float*)d_in[6];
  const float* Avec   = (const float*)d_in[7];
  const float* Dp     = (const float*)d_in[8];
  float* out = (float*)d_out;
  char* ws = (char*)d_ws;

  // weights -> bf16 (shared by both paths; layout prefix identical)
  u16* Win_bf  = (u16*)(ws + 0);          //  6,291,456
  u16* dtw_bf  = (u16*)(ws + 6291456);    //  4,718,592
  u16* Wout_bf = (u16*)(ws + 11010048);   //  3,145,728  -> end 14,155,776
  to_bf16<<<3072, 256, 0, stream>>>(W_in,  Win_bf,  786432);
  to_bf16<<<2304, 256, 0, stream>>>(dt_w,  dtw_bf,  589824);
  to_bf16<<<1536, 256, 0, stream>>>(W_out, Wout_bf, 393216);

  const size_t FULL_NEED = 249823232;   // full-batch layout
  if (ws_size >= FULL_NEED) {
    // ---------- full-batch path: M = 16384 ----------
    u16*   x_bf     = (u16*)  (ws + 14155776);    // 33,554,432  (16384x1024)
    u16*   xin_bf   = (u16*)  (ws + 47710208);    // 50,331,648  [w aliases]
    u16*   sz_bf    = (u16*)  (ws + 98041856);    // 50,331,648
    u16*   xconv_bf = (u16*)  (ws + 148373504);   // 50,331,648
    u16*   aexp_bf  = (u16*)  (ws + 198705152);   // 50,331,648  [y aliases]
    float* part     = (float*)(ws + 249036800);   //    786,432  (4x32x1536)
    u16*   w_bf     = xin_bf;
    u16*   y_bf     = aexp_bf;

    to_bf16<<<16384, 256, 0, stream>>>(x, x_bf, 4194304);

    // in_proj GEMM (M=16384, N=3072, K=1024): 8-phase EXPERIMENT
    gemm256<<<dim3(12, 64), 512, 0, stream>>>(x_bf, Win_bf,
                                              2 * DI, DIM_IN,
                                              xin_bf, sz_bf);
    // depthwise conv + SiLU
    conv_silu<<<24576, 256, 0, stream>>>(xin_bf, conv_w, conv_b, xconv_bf);

    // dt GEMM (M=16384, N=1536, K=1536): proven r3 kernel
    gemm_bt<2><<<dim3(12, 128), 256, 0, stream>>>(xconv_bf, dtw_bf, nullptr,
                                                  DI, DI,
                                                  w_bf, aexp_bf, xconv_bf, Avec, dt_b);

    // chunked prefix scan (offsets fused into apply) + pointwise tail
    scan_partial<<<dim3(6, NCHUNK, BATCH), 256, 0, stream>>>(w_bf, part);
    scan_apply<<<dim3(6, NCHUNK, BATCH), 256, 0, stream>>>(w_bf, part, aexp_bf,
                                                           xconv_bf, sz_bf, Dp, y_bf);

    // out_proj GEMM (M=16384, N=1024, K=1536): proven r3 kernel
    gemm_bt<0><<<dim3(8, 128), 256, 0, stream>>>(y_bf, Wout_bf, out,
                                                 DIM_IN, DI,
                                                 nullptr, nullptr, nullptr, nullptr, nullptr);
    return;
  }

  // ---------- per-batch fallback (73 MB), M = 4096: all-proven path ----------
  const size_t WS_NEED = 73072640;
  if (ws_size < WS_NEED) return;   // diagnostic: absmax=2096 w/o crash => ws too small

  u16*   x_bf     = (u16*)  (ws + 14155776);   //  8,388,608   (4096x1024)
  u16*   xin_bf   = (u16*)  (ws + 22544384);   // 12,582,912   [w aliases]
  u16*   sz_bf    = (u16*)  (ws + 35127296);   // 12,582,912
  u16*   xconv_bf = (u16*)  (ws + 47710208);   // 12,582,912
  u16*   aexp_bf  = (u16*)  (ws + 60293120);   // 12,582,912   [y aliases]
  float* part     = (float*)(ws + 72876032);   //    196,608
  u16*   w_bf     = xin_bf;
  u16*   y_bf     = aexp_bf;

  for (int b = 0; b < BATCH; b++) {
    const float* xb   = x   + (size_t)b * L_SEQ * DIM_IN;
    float*       outb = out + (size_t)b * L_SEQ * DIM_IN;

    to_bf16<<<4096, 256, 0, stream>>>(xb, x_bf, 1048576);
    gemm_bt<1><<<dim3(24, 32), 256, 0, stream>>>(x_bf, Win_bf, nullptr,
                                                 2 * DI, DIM_IN,
                                                 xin_bf, sz_bf, nullptr, nullptr, nullptr);
    conv_silu<<<6144, 256, 0, stream>>>(xin_bf, conv_w, conv_b, xconv_bf);
    gemm_bt<2><<<dim3(12, 32), 256, 0, stream>>>(xconv_bf, dtw_bf, nullptr,
                                                 DI, DI,
                                                 w_bf, aexp_bf, xconv_bf, Avec, dt_b);
    scan_partial<<<dim3(6, NCHUNK, 1), 256, 0, stream>>>(w_bf, part);
    scan_apply<<<dim3(6, NCHUNK, 1), 256, 0, stream>>>(w_bf, part, aexp_bf,
                                                       xconv_bf, sz_bf, Dp, y_bf);
    gemm_bt<0><<<dim3(8, 32), 256, 0, stream>>>(y_bf, Wout_bf, outb,
                                                DIM_IN, DI,
                                                nullptr, nullptr, nullptr, nullptr, nullptr);
  }
}

// Round 5
// 588.040 us; speedup vs baseline: 1.0137x; 1.0137x over previous
//
#include <hip/hip_runtime.h>
#include <cstdint>
#include <cstddef>

// ---------------- problem constants ----------------
#define L_SEQ   4096
#define DIM_IN  1024
#define DI      1536
#define BATCH   4

typedef unsigned short u16;
typedef __attribute__((ext_vector_type(8))) short  short8;   // 8 bf16 = 4 VGPRs
typedef __attribute__((ext_vector_type(4))) float  f32x4;

struct __align__(8) u16x4 { u16 x, y, z, w; };

// ---------------- helpers ----------------
__device__ __forceinline__ float bf2f(u16 u) {
  union { unsigned int i; float f; } v; v.i = ((unsigned int)u) << 16; return v.f;
}
__device__ __forceinline__ u16 f2bf(float f) {
  union { float f; unsigned int i; } v; v.f = f;
  unsigned int x = v.i;
  return (u16)((x + 0x7fffu + ((x >> 16) & 1u)) >> 16);   // RNE
}
__device__ __forceinline__ float siluf_(float v) {
  return v / (1.0f + __expf(-v));
}
__device__ __forceinline__ float softplusf_(float v) {
  return fmaxf(v, 0.0f) + log1pf(__expf(-fabsf(v)));
}
__device__ __forceinline__ void gload16(const void* g, void* l) {
  __builtin_amdgcn_global_load_lds((const __attribute__((address_space(1))) void*)g,
                                   (__attribute__((address_space(3))) void*)l,
                                   16, 0, 0);
}

// ---------------- fp32 -> bf16 convert ----------------
__global__ void to_bf16(const float* __restrict__ in, u16* __restrict__ out, int n4) {
  int i = blockIdx.x * blockDim.x + threadIdx.x;
  if (i >= n4) return;
  float4 v = ((const float4*)in)[i];
  u16x4 o;
  o.x = f2bf(v.x); o.y = f2bf(v.y); o.z = f2bf(v.z); o.w = f2bf(v.w);
  ((u16x4*)out)[i] = o;
}

// ---------------- bf16 MFMA GEMM, C = A(MxK) * Bt(NxK)^T ----------------
// r3-proven structure: 128x128 tile, BK=64, 4 waves 2x2, per-wave 64x64,
// both-sides LDS XOR swizzle (conflicts: 9.4M -> 0, r3-verified), bijective
// XCD block swizzle, single-buffer 2-barrier K-loop. 8-phase retired (r1/r2/r4:
// always behind this kernel at these shapes).
//
// EPI 0: plain fp32 C store (c_out, ld N)
// EPI 1: in_proj: col<DI -> bf16 x_inner e_bf_a; col>=DI -> silu -> bf16 e_bf1
// EPI 2: dt: dt=softplus(acc+e_v2[col]); a=exp(e_v1[col]*dt);
//        w = bf2f(e_bf2[row,col])*dt*a -> e_bf_a ; a -> e_bf1
//        NEW (r5): per-chunk column sums of w -> e_part (fuses scan_partial:
//        the 128-row tile IS one scan chunk; sums are already in registers).
template <int EPI>
__launch_bounds__(256, 3)
__global__ void gemm_bt(const u16* __restrict__ A, const u16* __restrict__ Bt,
                        float* __restrict__ c_out,
                        int N, int K,
                        u16* __restrict__ e_bf_a,
                        u16* __restrict__ e_bf1,
                        const u16* __restrict__ e_bf2,
                        const float* __restrict__ e_v1,
                        const float* __restrict__ e_v2,
                        float* __restrict__ e_part) {
  __shared__ u16 Alds[128 * 64];   // 16 KB
  __shared__ u16 Blds[128 * 64];   // 16 KB

  const int tid  = threadIdx.x;
  const int wave = tid >> 6;
  const int lane = tid & 63;
  const int quad = lane >> 4;
  const int l16  = lane & 15;

  // bijective XCD-aware block swizzle (nwg % 8 == 0 for every grid used here)
  const int nwg  = (int)(gridDim.x * gridDim.y);
  const int orig = (int)(blockIdx.y * gridDim.x + blockIdx.x);
  const int swz  = (orig & 7) * (nwg >> 3) + (orig >> 3);
  const int bx   = swz % (int)gridDim.x;
  const int by   = swz / (int)gridDim.x;
  const int m0 = by * 128;
  const int n0 = bx * 128;

  const int waveM = wave & 1;      // 2x2 wave grid
  const int waveN = wave >> 1;

  // staging: tile = 128 rows x 128 B; thread covers 4 x 16B chunks per matrix:
  // row = r*32 + (tid>>3), seg = tid&7, source col pre-swizzled by (row&7) so
  // the linear global_load_lds DMA lands the swizzled layout.
  const int srow = tid >> 3;                       // 0..31
  const int scol = ((tid & 7) ^ (srow & 7)) * 8;   // pre-swizzled source col (elems)
  const u16* Ap = A  + (size_t)(m0 + srow) * K + scol;
  const u16* Bp = Bt + (size_t)(n0 + srow) * K + scol;
  u16* adst = &Alds[tid * 8];
  u16* bdst = &Blds[tid * 8];

  const unsigned xorc = (unsigned)(l16 & 7) << 3;  // read-side involution (elems)

  f32x4 acc[4][4] = {};

  for (int k0 = 0; k0 < K; k0 += 64) {
#pragma unroll
    for (int r = 0; r < 4; ++r) {
      gload16(Ap + (size_t)(r * 32) * K + k0, adst + r * 2048);
      gload16(Bp + (size_t)(r * 32) * K + k0, bdst + r * 2048);
    }
    __syncthreads();

#pragma unroll
    for (int kb = 0; kb < 2; ++kb) {
      short8 af[4], bf[4];
      const unsigned ck = (unsigned)(kb * 32 + quad * 8) ^ xorc;
#pragma unroll
      for (int i = 0; i < 4; i++) {
        af[i] = *(const short8*)&Alds[(unsigned)(waveM * 64 + i * 16 + l16) * 64 + ck];
        bf[i] = *(const short8*)&Blds[(unsigned)(waveN * 64 + i * 16 + l16) * 64 + ck];
      }
#pragma unroll
      for (int mi = 0; mi < 4; mi++)
#pragma unroll
        for (int ni = 0; ni < 4; ni++)
          acc[mi][ni] = __builtin_amdgcn_mfma_f32_16x16x32_bf16(af[mi], bf[ni],
                                                                acc[mi][ni], 0, 0, 0);
    }
    __syncthreads();
  }

  // epilogue: C/D layout col=lane&15, row=quad*4+reg (m89/m91-verified)
  float colsum[4] = {0.0f, 0.0f, 0.0f, 0.0f};   // EPI2: per-ni column partial sums
#pragma unroll
  for (int mi = 0; mi < 4; mi++) {
    const int rowBase = m0 + waveM * 64 + mi * 16 + quad * 4;
#pragma unroll
    for (int ni = 0; ni < 4; ni++) {
      const int gcol = n0 + waveN * 64 + ni * 16 + l16;
#pragma unroll
      for (int r = 0; r < 4; r++) {
        const float v = acc[mi][ni][r];
        const size_t row = (size_t)(rowBase + r);
        if constexpr (EPI == 0) {
          c_out[row * (size_t)N + gcol] = v;
        } else if constexpr (EPI == 1) {
          if (gcol < DI) {
            e_bf_a[row * DI + gcol] = f2bf(v);
          } else {
            e_bf1[row * DI + (gcol - DI)] = f2bf(siluf_(v));
          }
        } else {
          const float dt = softplusf_(v + e_v2[gcol]);
          const float a  = __expf(e_v1[gcol] * dt);
          const float xc = bf2f(e_bf2[row * DI + gcol]);
          const float w  = xc * dt * a;
          e_bf_a[row * DI + gcol] = f2bf(w);
          e_bf1[row * DI + gcol] = f2bf(a);
          colsum[ni] += w;
        }
      }
    }
  }

  if constexpr (EPI == 2) {
    // fused scan_partial: tile rows [m0, m0+128) == scan chunk m0>>7; each
    // column's 128 rows live in {waveM} x {quad} x {mi,r}. In-thread sum done
    // above (mi,r); quad-reduce via shfl_xor; waveM-reduce via LDS (free now).
#pragma unroll
    for (int ni = 0; ni < 4; ++ni) {
      colsum[ni] += __shfl_xor(colsum[ni], 16);
      colsum[ni] += __shfl_xor(colsum[ni], 32);
    }
    float* red = (float*)&Alds[0];   // 2 waveN x 4 ni x 16 l16 = 128 floats
    if (waveM == 0 && quad == 0) {
#pragma unroll
      for (int ni = 0; ni < 4; ++ni)
        red[(waveN * 4 + ni) * 16 + l16] = colsum[ni];
    }
    __syncthreads();
    if (waveM == 1 && quad == 0) {
      const int chunk = m0 >> 7;
#pragma unroll
      for (int ni = 0; ni < 4; ++ni) {
        const int c = n0 + waveN * 64 + ni * 16 + l16;
        e_part[(size_t)chunk * DI + c] = colsum[ni] + red[(waveN * 4 + ni) * 16 + l16];
      }
    }
  }
}

// ---------------- depthwise conv1d(k=3,pad=1) + bias + SiLU ----------------------
__global__ void conv_silu(const u16* __restrict__ xin, const float* __restrict__ cw,
                          const float* __restrict__ cb, u16* __restrict__ xconv_bf) {
  const int idx = blockIdx.x * blockDim.x + threadIdx.x;   // one thread = 4 channels
  const int c4  = (idx % (DI / 4)) * 4;
  const int row = idx / (DI / 4);
  const int l   = row & (L_SEQ - 1);

  const size_t base = (size_t)row * DI + c4;
  u16x4 z4 = {0, 0, 0, 0};
  u16x4 x1 = *(const u16x4*)(xin + base);
  u16x4 x0 = (l > 0)         ? *(const u16x4*)(xin + base - DI) : z4;
  u16x4 x2 = (l < L_SEQ - 1) ? *(const u16x4*)(xin + base + DI) : z4;

  const u16* p0 = (const u16*)&x0;
  const u16* p1 = (const u16*)&x1;
  const u16* p2 = (const u16*)&x2;
  u16x4 o;
  u16* po = (u16*)&o;
#pragma unroll
  for (int j = 0; j < 4; j++) {
    const int c = c4 + j;
    float v = fmaf(cw[c * 3 + 0], bf2f(p0[j]),
              fmaf(cw[c * 3 + 1], bf2f(p1[j]),
                   cw[c * 3 + 2] * bf2f(p2[j]))) + cb[c];
    po[j] = f2bf(siluf_(v));
  }
  *(u16x4*)&xconv_bf[base] = o;
}

// ---------------- chunked prefix scan over L (chunk=128, 32 chunks/batch) --------
#define CHUNK 128
#define NCHUNK (L_SEQ / CHUNK)   // 32

// partial[] holds PER-CHUNK SUMS (written by the fused dt epilogue); each block
// prefix-sums the chunks before its own (scan_offsets folded in, r4-verified).
// NOTE: ybf aliases aexp (same index read-then-write per thread) — no __restrict__.
__global__ void scan_apply(const u16* __restrict__ w, const float* __restrict__ partial,
                           const u16* aexp, const u16* __restrict__ xconv,
                           const u16* __restrict__ sz, const float* __restrict__ Dp,
                           u16* ybf) {
  const int c  = blockIdx.x * 256 + threadIdx.x;
  const int ch = blockIdx.y;
  const int b  = blockIdx.z;
  float run = 0.0f;
  for (int j = 0; j < ch; ++j)
    run += partial[((size_t)b * NCHUNK + j) * DI + c];
  const float dp = Dp[c];
  size_t base = ((size_t)b * L_SEQ + (size_t)ch * CHUNK) * DI + c;
  for (int i = 0; i < CHUNK; i++) {
    size_t p = base + (size_t)i * DI;
    float ae = bf2f(aexp[p]);             // read BEFORE the aliased write
    run += bf2f(w[p]);
    float y = run * ae + bf2f(xconv[p]) * dp;
    y *= bf2f(sz[p]);
    ybf[p] = f2bf(y);
  }
}

// ---------------- launcher ----------------
extern "C" void kernel_launch(void* const* d_in, const int* in_sizes, int n_in,
                              void* d_out, int out_size, void* d_ws, size_t ws_size,
                              hipStream_t stream) {
  const float* x      = (const float*)d_in[0];
  const float* W_in   = (const float*)d_in[1];   // (3072,1024)
  const float* W_out  = (const float*)d_in[2];   // (1024,1536)
  const float* conv_w = (const float*)d_in[3];   // (1536,1,3)
  const float* conv_b = (const float*)d_in[4];
  const float* dt_w   = (const float*)d_in[5];   // (1536,1536)
  const float* dt_b   = (const float*)d_in[6];
  const float* Avec   = (const float*)d_in[7];
  const float* Dp     = (const float*)d_in[8];
  float* out = (float*)d_out;
  char* ws = (char*)d_ws;

  // weights -> bf16 (shared by both paths; layout prefix identical)
  u16* Win_bf  = (u16*)(ws + 0);          //  6,291,456
  u16* dtw_bf  = (u16*)(ws + 6291456);    //  4,718,592
  u16* Wout_bf = (u16*)(ws + 11010048);   //  3,145,728  -> end 14,155,776
  to_bf16<<<3072, 256, 0, stream>>>(W_in,  Win_bf,  786432);
  to_bf16<<<2304, 256, 0, stream>>>(dt_w,  dtw_bf,  589824);
  to_bf16<<<1536, 256, 0, stream>>>(W_out, Wout_bf, 393216);

  const size_t FULL_NEED = 249823232;   // full-batch layout
  if (ws_size >= FULL_NEED) {
    // ---------- full-batch path: M = 16384 ----------
    u16*   x_bf     = (u16*)  (ws + 14155776);    // 33,554,432  (16384x1024)
    u16*   xin_bf   = (u16*)  (ws + 47710208);    // 50,331,648  [w aliases]
    u16*   sz_bf    = (u16*)  (ws + 98041856);    // 50,331,648
    u16*   xconv_bf = (u16*)  (ws + 148373504);   // 50,331,648
    u16*   aexp_bf  = (u16*)  (ws + 198705152);   // 50,331,648  [y aliases]
    float* part     = (float*)(ws + 249036800);   //    786,432  (4x32x1536)
    u16*   w_bf     = xin_bf;
    u16*   y_bf     = aexp_bf;

    to_bf16<<<16384, 256, 0, stream>>>(x, x_bf, 4194304);

    // in_proj GEMM (M=16384, N=3072, K=1024) + split epilogue  [r3-proven]
    gemm_bt<1><<<dim3(24, 128), 256, 0, stream>>>(x_bf, Win_bf, nullptr,
                                                  2 * DI, DIM_IN,
                                                  xin_bf, sz_bf, nullptr, nullptr, nullptr,
                                                  nullptr);
    // depthwise conv + SiLU (batch edges via l = row & 4095)
    conv_silu<<<24576, 256, 0, stream>>>(xin_bf, conv_w, conv_b, xconv_bf);

    // dt GEMM (M=16384, N=1536, K=1536) + softplus/exp/w epilogue
    // + fused per-chunk column sums -> part (replaces scan_partial)
    gemm_bt<2><<<dim3(12, 128), 256, 0, stream>>>(xconv_bf, dtw_bf, nullptr,
                                                  DI, DI,
                                                  w_bf, aexp_bf, xconv_bf, Avec, dt_b,
                                                  part);

    // prefix-apply (chunk offsets computed in-block from per-chunk sums)
    scan_apply<<<dim3(6, NCHUNK, BATCH), 256, 0, stream>>>(w_bf, part, aexp_bf,
                                                           xconv_bf, sz_bf, Dp, y_bf);

    // out_proj GEMM (M=16384, N=1024, K=1536) -> fp32 output
    gemm_bt<0><<<dim3(8, 128), 256, 0, stream>>>(y_bf, Wout_bf, out,
                                                 DIM_IN, DI,
                                                 nullptr, nullptr, nullptr, nullptr, nullptr,
                                                 nullptr);
    return;
  }

  // ---------- per-batch fallback (73 MB), M = 4096 ----------
  const size_t WS_NEED = 73072640;
  if (ws_size < WS_NEED) return;   // diagnostic: absmax=2096 w/o crash => ws too small

  u16*   x_bf     = (u16*)  (ws + 14155776);   //  8,388,608   (4096x1024)
  u16*   xin_bf   = (u16*)  (ws + 22544384);   // 12,582,912   [w aliases]
  u16*   sz_bf    = (u16*)  (ws + 35127296);   // 12,582,912
  u16*   xconv_bf = (u16*)  (ws + 47710208);   // 12,582,912
  u16*   aexp_bf  = (u16*)  (ws + 60293120);   // 12,582,912   [y aliases]
  float* part     = (float*)(ws + 72876032);   //    196,608
  u16*   w_bf     = xin_bf;
  u16*   y_bf     = aexp_bf;

  for (int b = 0; b < BATCH; b++) {
    const float* xb   = x   + (size_t)b * L_SEQ * DIM_IN;
    float*       outb = out + (size_t)b * L_SEQ * DIM_IN;

    to_bf16<<<4096, 256, 0, stream>>>(xb, x_bf, 1048576);
    gemm_bt<1><<<dim3(24, 32), 256, 0, stream>>>(x_bf, Win_bf, nullptr,
                                                 2 * DI, DIM_IN,
                                                 xin_bf, sz_bf, nullptr, nullptr, nullptr,
                                                 nullptr);
    conv_silu<<<6144, 256, 0, stream>>>(xin_bf, conv_w, conv_b, xconv_bf);
    gemm_bt<2><<<dim3(12, 32), 256, 0, stream>>>(xconv_bf, dtw_bf, nullptr,
                                                 DI, DI,
                                                 w_bf, aexp_bf, xconv_bf, Avec, dt_b,
                                                 part);
    scan_apply<<<dim3(6, NCHUNK, 1), 256, 0, stream>>>(w_bf, part, aexp_bf,
                                                       xconv_bf, sz_bf, Dp, y_bf);
    gemm_bt<0><<<dim3(8, 32), 256, 0, stream>>>(y_bf, Wout_bf, outb,
                                                DIM_IN, DI,
                                                nullptr, nullptr, nullptr, nullptr, nullptr,
                                                nullptr);
  }
}

// Round 6
// 524.901 us; speedup vs baseline: 1.1357x; 1.1203x over previous
//
#include <hip/hip_runtime.h>
#include <cstdint>
#include <cstddef>

// ---------------- problem constants ----------------
#define L_SEQ   4096
#define DIM_IN  1024
#define DI      1536
#define BATCH   4

typedef unsigned short u16;
typedef __attribute__((ext_vector_type(8))) short  short8;   // 8 bf16 = 4 VGPRs
typedef __attribute__((ext_vector_type(4))) float  f32x4;

struct __align__(8) u16x4 { u16 x, y, z, w; };

// ---------------- helpers ----------------
__device__ __forceinline__ float bf2f(u16 u) {
  union { unsigned int i; float f; } v; v.i = ((unsigned int)u) << 16; return v.f;
}
__device__ __forceinline__ u16 f2bf(float f) {
  union { float f; unsigned int i; } v; v.f = f;
  unsigned int x = v.i;
  return (u16)((x + 0x7fffu + ((x >> 16) & 1u)) >> 16);   // RNE
}
__device__ __forceinline__ float siluf_(float v) {
  return v / (1.0f + __expf(-v));
}
// r6: __logf(1+x) instead of libm log1pf — x in (0,1] so abs error << bf16
// rounding; removes a long libm sequence from the dt epilogue (64x per thread).
__device__ __forceinline__ float softplusf_(float v) {
  return fmaxf(v, 0.0f) + __logf(1.0f + __expf(-fabsf(v)));
}
__device__ __forceinline__ void gload16(const void* g, void* l) {
  __builtin_amdgcn_global_load_lds((const __attribute__((address_space(1))) void*)g,
                                   (__attribute__((address_space(3))) void*)l,
                                   16, 0, 0);
}

// ---------------- fp32 -> bf16 convert ----------------
__global__ void to_bf16(const float* __restrict__ in, u16* __restrict__ out, int n4) {
  int i = blockIdx.x * blockDim.x + threadIdx.x;
  if (i >= n4) return;
  float4 v = ((const float4*)in)[i];
  u16x4 o;
  o.x = f2bf(v.x); o.y = f2bf(v.y); o.z = f2bf(v.z); o.w = f2bf(v.w);
  ((u16x4*)out)[i] = o;
}

// ---------------- bf16 MFMA GEMM, C = A(MxK) * Bt(NxK)^T ----------------
// r3-proven structure: 128x128 tile, BK=64, 4 waves 2x2, per-wave 64x64,
// both-sides LDS XOR swizzle (conflicts 9.4M -> 0), bijective XCD block
// swizzle, single-buffer 2-barrier K-loop.
//
// EPI 0: plain fp32 C store (c_out, ld N)
// EPI 1: in_proj: col<DI -> bf16 x_inner e_bf_a; col>=DI -> silu -> bf16 e_bf1
// EPI 2: dt: dt=softplus(acc+e_v2[col]); a=exp(e_v1[col]*dt);
//        w = bf2f(e_bf2[row,col])*dt*a -> e_bf_a ; a -> e_bf1
//        + fused scan_partial as TWO per-half sums (r6): after shfl_xor(16/32)
//        every lane holds its column's 64-row sum for its waveM half; quad==0
//        lanes store e_part[chunk][waveM][c] directly. NO LDS, NO __syncthreads
//        (r5's barrier forced a vmcnt(0) drain of the epilogue's scattered
//        stores inside the kernel -> +19 us; this removes that entirely).
template <int EPI>
__launch_bounds__(256, 3)
__global__ void gemm_bt(const u16* __restrict__ A, const u16* __restrict__ Bt,
                        float* __restrict__ c_out,
                        int N, int K,
                        u16* __restrict__ e_bf_a,
                        u16* __restrict__ e_bf1,
                        const u16* __restrict__ e_bf2,
                        const float* __restrict__ e_v1,
                        const float* __restrict__ e_v2,
                        float* __restrict__ e_part) {
  __shared__ u16 Alds[128 * 64];   // 16 KB
  __shared__ u16 Blds[128 * 64];   // 16 KB

  const int tid  = threadIdx.x;
  const int wave = tid >> 6;
  const int lane = tid & 63;
  const int quad = lane >> 4;
  const int l16  = lane & 15;

  // bijective XCD-aware block swizzle (nwg % 8 == 0 for every grid used here)
  const int nwg  = (int)(gridDim.x * gridDim.y);
  const int orig = (int)(blockIdx.y * gridDim.x + blockIdx.x);
  const int swz  = (orig & 7) * (nwg >> 3) + (orig >> 3);
  const int bx   = swz % (int)gridDim.x;
  const int by   = swz / (int)gridDim.x;
  const int m0 = by * 128;
  const int n0 = bx * 128;

  const int waveM = wave & 1;      // 2x2 wave grid
  const int waveN = wave >> 1;

  // staging: tile = 128 rows x 128 B; thread covers 4 x 16B chunks per matrix:
  // row = r*32 + (tid>>3), seg = tid&7, source col pre-swizzled by (row&7) so
  // the linear global_load_lds DMA lands the swizzled layout.
  const int srow = tid >> 3;                       // 0..31
  const int scol = ((tid & 7) ^ (srow & 7)) * 8;   // pre-swizzled source col (elems)
  const u16* Ap = A  + (size_t)(m0 + srow) * K + scol;
  const u16* Bp = Bt + (size_t)(n0 + srow) * K + scol;
  u16* adst = &Alds[tid * 8];
  u16* bdst = &Blds[tid * 8];

  const unsigned xorc = (unsigned)(l16 & 7) << 3;  // read-side involution (elems)

  f32x4 acc[4][4] = {};

  for (int k0 = 0; k0 < K; k0 += 64) {
#pragma unroll
    for (int r = 0; r < 4; ++r) {
      gload16(Ap + (size_t)(r * 32) * K + k0, adst + r * 2048);
      gload16(Bp + (size_t)(r * 32) * K + k0, bdst + r * 2048);
    }
    __syncthreads();

#pragma unroll
    for (int kb = 0; kb < 2; ++kb) {
      short8 af[4], bf[4];
      const unsigned ck = (unsigned)(kb * 32 + quad * 8) ^ xorc;
#pragma unroll
      for (int i = 0; i < 4; i++) {
        af[i] = *(const short8*)&Alds[(unsigned)(waveM * 64 + i * 16 + l16) * 64 + ck];
        bf[i] = *(const short8*)&Blds[(unsigned)(waveN * 64 + i * 16 + l16) * 64 + ck];
      }
#pragma unroll
      for (int mi = 0; mi < 4; mi++)
#pragma unroll
        for (int ni = 0; ni < 4; ni++)
          acc[mi][ni] = __builtin_amdgcn_mfma_f32_16x16x32_bf16(af[mi], bf[ni],
                                                                acc[mi][ni], 0, 0, 0);
    }
    __syncthreads();
  }

  // epilogue: C/D layout col=lane&15, row=quad*4+reg (m89/m91-verified)
  float colsum[4] = {0.0f, 0.0f, 0.0f, 0.0f};   // EPI2: per-ni column partials
#pragma unroll
  for (int mi = 0; mi < 4; mi++) {
    const int rowBase = m0 + waveM * 64 + mi * 16 + quad * 4;
#pragma unroll
    for (int ni = 0; ni < 4; ni++) {
      const int gcol = n0 + waveN * 64 + ni * 16 + l16;
#pragma unroll
      for (int r = 0; r < 4; r++) {
        const float v = acc[mi][ni][r];
        const size_t row = (size_t)(rowBase + r);
        if constexpr (EPI == 0) {
          c_out[row * (size_t)N + gcol] = v;
        } else if constexpr (EPI == 1) {
          if (gcol < DI) {
            e_bf_a[row * DI + gcol] = f2bf(v);
          } else {
            e_bf1[row * DI + (gcol - DI)] = f2bf(siluf_(v));
          }
        } else {
          const float dt = softplusf_(v + e_v2[gcol]);
          const float a  = __expf(e_v1[gcol] * dt);
          const float xc = bf2f(e_bf2[row * DI + gcol]);
          const float w  = xc * dt * a;
          e_bf_a[row * DI + gcol] = f2bf(w);
          e_bf1[row * DI + gcol] = f2bf(a);
          colsum[ni] += w;
        }
      }
    }
  }

  if constexpr (EPI == 2) {
    // fused scan_partial, barrier-free: thread sum covers {mi,r} (16 rows);
    // shfl_xor over the two quad bits folds in quad*4 -> full 64-row sum of
    // this waveM half, replicated in all lanes. quad==0 lanes store the half.
#pragma unroll
    for (int ni = 0; ni < 4; ++ni) {
      colsum[ni] += __shfl_xor(colsum[ni], 16);
      colsum[ni] += __shfl_xor(colsum[ni], 32);
    }
    if (quad == 0) {
      const int chunk = m0 >> 7;
#pragma unroll
      for (int ni = 0; ni < 4; ++ni) {
        const int c = n0 + waveN * 64 + ni * 16 + l16;
        e_part[((size_t)chunk * 2 + waveM) * DI + c] = colsum[ni];
      }
    }
  }
}

// ---------------- depthwise conv1d(k=3,pad=1) + bias + SiLU ----------------------
__global__ void conv_silu(const u16* __restrict__ xin, const float* __restrict__ cw,
                          const float* __restrict__ cb, u16* __restrict__ xconv_bf) {
  const int idx = blockIdx.x * blockDim.x + threadIdx.x;   // one thread = 4 channels
  const int c4  = (idx % (DI / 4)) * 4;
  const int row = idx / (DI / 4);
  const int l   = row & (L_SEQ - 1);

  const size_t base = (size_t)row * DI + c4;
  u16x4 z4 = {0, 0, 0, 0};
  u16x4 x1 = *(const u16x4*)(xin + base);
  u16x4 x0 = (l > 0)         ? *(const u16x4*)(xin + base - DI) : z4;
  u16x4 x2 = (l < L_SEQ - 1) ? *(const u16x4*)(xin + base + DI) : z4;

  const u16* p0 = (const u16*)&x0;
  const u16* p1 = (const u16*)&x1;
  const u16* p2 = (const u16*)&x2;
  u16x4 o;
  u16* po = (u16*)&o;
#pragma unroll
  for (int j = 0; j < 4; j++) {
    const int c = c4 + j;
    float v = fmaf(cw[c * 3 + 0], bf2f(p0[j]),
              fmaf(cw[c * 3 + 1], bf2f(p1[j]),
                   cw[c * 3 + 2] * bf2f(p2[j]))) + cb[c];
    po[j] = f2bf(siluf_(v));
  }
  *(u16x4*)&xconv_bf[base] = o;
}

// ---------------- chunked prefix scan over L (chunk=128, 32 chunks/batch) --------
#define CHUNK 128
#define NCHUNK (L_SEQ / CHUNK)   // 32

// partial[] holds TWO per-half sums per chunk ([chunk][2][DI], written by the
// fused dt epilogue); each block prefix-sums the chunks before its own.
// NOTE: ybf aliases aexp (same index read-then-write per thread) — no __restrict__.
__global__ void scan_apply(const u16* __restrict__ w, const float* __restrict__ partial,
                           const u16* aexp, const u16* __restrict__ xconv,
                           const u16* __restrict__ sz, const float* __restrict__ Dp,
                           u16* ybf) {
  const int c  = blockIdx.x * 256 + threadIdx.x;
  const int ch = blockIdx.y;
  const int b  = blockIdx.z;
  float run = 0.0f;
  const float* pb = partial + (size_t)(b * NCHUNK) * 2 * DI + c;
  for (int j = 0; j < ch; ++j)
    run += pb[(size_t)j * 2 * DI] + pb[(size_t)j * 2 * DI + DI];
  const float dp = Dp[c];
  size_t base = ((size_t)b * L_SEQ + (size_t)ch * CHUNK) * DI + c;
  for (int i = 0; i < CHUNK; i++) {
    size_t p = base + (size_t)i * DI;
    float ae = bf2f(aexp[p]);             // read BEFORE the aliased write
    run += bf2f(w[p]);
    float y = run * ae + bf2f(xconv[p]) * dp;
    y *= bf2f(sz[p]);
    ybf[p] = f2bf(y);
  }
}

// ---------------- launcher ----------------
extern "C" void kernel_launch(void* const* d_in, const int* in_sizes, int n_in,
                              void* d_out, int out_size, void* d_ws, size_t ws_size,
                              hipStream_t stream) {
  const float* x      = (const float*)d_in[0];
  const float* W_in   = (const float*)d_in[1];   // (3072,1024)
  const float* W_out  = (const float*)d_in[2];   // (1024,1536)
  const float* conv_w = (const float*)d_in[3];   // (1536,1,3)
  const float* conv_b = (const float*)d_in[4];
  const float* dt_w   = (const float*)d_in[5];   // (1536,1536)
  const float* dt_b   = (const float*)d_in[6];
  const float* Avec   = (const float*)d_in[7];
  const float* Dp     = (const float*)d_in[8];
  float* out = (float*)d_out;
  char* ws = (char*)d_ws;

  // weights -> bf16 (shared by both paths; layout prefix identical)
  u16* Win_bf  = (u16*)(ws + 0);          //  6,291,456
  u16* dtw_bf  = (u16*)(ws + 6291456);    //  4,718,592
  u16* Wout_bf = (u16*)(ws + 11010048);   //  3,145,728  -> end 14,155,776
  to_bf16<<<3072, 256, 0, stream>>>(W_in,  Win_bf,  786432);
  to_bf16<<<2304, 256, 0, stream>>>(dt_w,  dtw_bf,  589824);
  to_bf16<<<1536, 256, 0, stream>>>(W_out, Wout_bf, 393216);

  const size_t FULL_NEED = 249823232;   // full-batch layout
  if (ws_size >= FULL_NEED) {
    // ---------- full-batch path: M = 16384 ----------
    u16*   x_bf     = (u16*)  (ws + 14155776);    // 33,554,432  (16384x1024)
    u16*   xin_bf   = (u16*)  (ws + 47710208);    // 50,331,648  [w aliases]
    u16*   sz_bf    = (u16*)  (ws + 98041856);    // 50,331,648
    u16*   xconv_bf = (u16*)  (ws + 148373504);   // 50,331,648
    u16*   aexp_bf  = (u16*)  (ws + 198705152);   // 50,331,648  [y aliases]
    u16*   w_bf     = xin_bf;
    u16*   y_bf     = aexp_bf;
    // part2 [128 chunks][2][DI] f32 = 1,572,864 B: aliases x_bf (dead after
    // in_proj; dt writes it strictly later in stream order).
    float* part     = (float*)x_bf;

    to_bf16<<<16384, 256, 0, stream>>>(x, x_bf, 4194304);

    // in_proj GEMM (M=16384, N=3072, K=1024) + split epilogue  [r3-proven]
    gemm_bt<1><<<dim3(24, 128), 256, 0, stream>>>(x_bf, Win_bf, nullptr,
                                                  2 * DI, DIM_IN,
                                                  xin_bf, sz_bf, nullptr, nullptr, nullptr,
                                                  nullptr);
    // depthwise conv + SiLU (batch edges via l = row & 4095)
    conv_silu<<<24576, 256, 0, stream>>>(xin_bf, conv_w, conv_b, xconv_bf);

    // dt GEMM (M=16384, N=1536, K=1536) + softplus/exp/w epilogue
    // + fused barrier-free per-chunk half-sums -> part (replaces scan_partial)
    gemm_bt<2><<<dim3(12, 128), 256, 0, stream>>>(xconv_bf, dtw_bf, nullptr,
                                                  DI, DI,
                                                  w_bf, aexp_bf, xconv_bf, Avec, dt_b,
                                                  part);

    // prefix-apply (chunk offsets computed in-block from per-chunk half-sums)
    scan_apply<<<dim3(6, NCHUNK, BATCH), 256, 0, stream>>>(w_bf, part, aexp_bf,
                                                           xconv_bf, sz_bf, Dp, y_bf);

    // out_proj GEMM (M=16384, N=1024, K=1536) -> fp32 output
    gemm_bt<0><<<dim3(8, 128), 256, 0, stream>>>(y_bf, Wout_bf, out,
                                                 DIM_IN, DI,
                                                 nullptr, nullptr, nullptr, nullptr, nullptr,
                                                 nullptr);
    return;
  }

  // ---------- per-batch fallback (73 MB), M = 4096 ----------
  const size_t WS_NEED = 73072640;
  if (ws_size < WS_NEED) return;   // diagnostic: absmax=2096 w/o crash => ws too small

  u16*   x_bf     = (u16*)  (ws + 14155776);   //  8,388,608   (4096x1024)
  u16*   xin_bf   = (u16*)  (ws + 22544384);   // 12,582,912   [w aliases]
  u16*   sz_bf    = (u16*)  (ws + 35127296);   // 12,582,912
  u16*   xconv_bf = (u16*)  (ws + 47710208);   // 12,582,912
  u16*   aexp_bf  = (u16*)  (ws + 60293120);   // 12,582,912   [y aliases]
  u16*   w_bf     = xin_bf;
  u16*   y_bf     = aexp_bf;
  // part2 [32 chunks][2][DI] f32 = 393,216 B: aliases x_bf (dead after in_proj
  // of the same batch; rewritten by next batch's to_bf16 only after scan_apply).
  float* part     = (float*)x_bf;

  for (int b = 0; b < BATCH; b++) {
    const float* xb   = x   + (size_t)b * L_SEQ * DIM_IN;
    float*       outb = out + (size_t)b * L_SEQ * DIM_IN;

    to_bf16<<<4096, 256, 0, stream>>>(xb, x_bf, 1048576);
    gemm_bt<1><<<dim3(24, 32), 256, 0, stream>>>(x_bf, Win_bf, nullptr,
                                                 2 * DI, DIM_IN,
                                                 xin_bf, sz_bf, nullptr, nullptr, nullptr,
                                                 nullptr);
    conv_silu<<<6144, 256, 0, stream>>>(xin_bf, conv_w, conv_b, xconv_bf);
    gemm_bt<2><<<dim3(12, 32), 256, 0, stream>>>(xconv_bf, dtw_bf, nullptr,
                                                 DI, DI,
                                                 w_bf, aexp_bf, xconv_bf, Avec, dt_b,
                                                 part);
    scan_apply<<<dim3(6, NCHUNK, 1), 256, 0, stream>>>(w_bf, part, aexp_bf,
                                                       xconv_bf, sz_bf, Dp, y_bf);
    gemm_bt<0><<<dim3(8, 32), 256, 0, stream>>>(y_bf, Wout_bf, outb,
                                                DIM_IN, DI,
                                                nullptr, nullptr, nullptr, nullptr, nullptr,
                                                nullptr);
  }
}

// Round 7
// 499.765 us; speedup vs baseline: 1.1928x; 1.0503x over previous
//
#include <hip/hip_runtime.h>
#include <cstdint>
#include <cstddef>

// ---------------- problem constants ----------------
#define L_SEQ   4096
#define DIM_IN  1024
#define DI      1536
#define BATCH   4

typedef unsigned short u16;
typedef __attribute__((ext_vector_type(8))) short  short8;   // 8 bf16 = 4 VGPRs
typedef __attribute__((ext_vector_type(4))) float  f32x4;

struct __align__(8) u16x4 { u16 x, y, z, w; };

// ---------------- helpers ----------------
__device__ __forceinline__ float bf2f(u16 u) {
  union { unsigned int i; float f; } v; v.i = ((unsigned int)u) << 16; return v.f;
}
__device__ __forceinline__ u16 f2bf(float f) {
  union { float f; unsigned int i; } v; v.f = f;
  unsigned int x = v.i;
  return (u16)((x + 0x7fffu + ((x >> 16) & 1u)) >> 16);   // RNE
}
__device__ __forceinline__ float siluf_(float v) {
  return v / (1.0f + __expf(-v));
}
// __logf(1+x), x in (0,1]: abs error << bf16 rounding (r6-verified)
__device__ __forceinline__ float softplusf_(float v) {
  return fmaxf(v, 0.0f) + __logf(1.0f + __expf(-fabsf(v)));
}
__device__ __forceinline__ void gload16(const void* g, void* l) {
  __builtin_amdgcn_global_load_lds((const __attribute__((address_space(1))) void*)g,
                                   (__attribute__((address_space(3))) void*)l,
                                   16, 0, 0);
}

// ---------------- fp32 -> bf16 convert ----------------
__global__ void to_bf16(const float* __restrict__ in, u16* __restrict__ out, int n4) {
  int i = blockIdx.x * blockDim.x + threadIdx.x;
  if (i >= n4) return;
  float4 v = ((const float4*)in)[i];
  u16x4 o;
  o.x = f2bf(v.x); o.y = f2bf(v.y); o.z = f2bf(v.z); o.w = f2bf(v.w);
  ((u16x4*)out)[i] = o;
}

// ---------------- bf16 MFMA GEMM, C = A(MxK) * Bt(NxK)^T ----------------
// r3-proven structure: 128x128 tile, BK=64, 4 waves 2x2, per-wave 64x64,
// both-sides LDS XOR swizzle (conflicts 9.4M -> 0), bijective XCD block
// swizzle, single-buffer 2-barrier K-loop.
//
// EPI 0: plain fp32 C store (c_out, ld N)
// EPI 1: in_proj: col<DI -> bf16 x_inner e_bf_a; col>=DI -> silu -> bf16 e_bf1
// EPI 2: dt: dt=softplus(acc+e_v2[col]); a=exp(e_v1[col]*dt);
//        w = bf2f(e_bf2[row,col])*dt*a -> e_bf_a ; a -> e_bf1
//        + fused scan_partial as TWO per-half sums, barrier-free (r6-proven).
template <int EPI>
__launch_bounds__(256, 3)
__global__ void gemm_bt(const u16* __restrict__ A, const u16* __restrict__ Bt,
                        float* __restrict__ c_out,
                        int N, int K,
                        u16* __restrict__ e_bf_a,
                        u16* __restrict__ e_bf1,
                        const u16* __restrict__ e_bf2,
                        const float* __restrict__ e_v1,
                        const float* __restrict__ e_v2,
                        float* __restrict__ e_part) {
  __shared__ u16 Alds[128 * 64];   // 16 KB
  __shared__ u16 Blds[128 * 64];   // 16 KB

  const int tid  = threadIdx.x;
  const int wave = tid >> 6;
  const int lane = tid & 63;
  const int quad = lane >> 4;
  const int l16  = lane & 15;

  // bijective XCD-aware block swizzle (nwg % 8 == 0 for every grid used here)
  const int nwg  = (int)(gridDim.x * gridDim.y);
  const int orig = (int)(blockIdx.y * gridDim.x + blockIdx.x);
  const int swz  = (orig & 7) * (nwg >> 3) + (orig >> 3);
  const int bx   = swz % (int)gridDim.x;
  const int by   = swz / (int)gridDim.x;
  const int m0 = by * 128;
  const int n0 = bx * 128;

  const int waveM = wave & 1;      // 2x2 wave grid
  const int waveN = wave >> 1;

  // staging: tile = 128 rows x 128 B; thread covers 4 x 16B chunks per matrix:
  // row = r*32 + (tid>>3), seg = tid&7, source col pre-swizzled by (row&7) so
  // the linear global_load_lds DMA lands the swizzled layout.
  const int srow = tid >> 3;                       // 0..31
  const int scol = ((tid & 7) ^ (srow & 7)) * 8;   // pre-swizzled source col (elems)
  const u16* Ap = A  + (size_t)(m0 + srow) * K + scol;
  const u16* Bp = Bt + (size_t)(n0 + srow) * K + scol;
  u16* adst = &Alds[tid * 8];
  u16* bdst = &Blds[tid * 8];

  const unsigned xorc = (unsigned)(l16 & 7) << 3;  // read-side involution (elems)

  f32x4 acc[4][4] = {};

  for (int k0 = 0; k0 < K; k0 += 64) {
#pragma unroll
    for (int r = 0; r < 4; ++r) {
      gload16(Ap + (size_t)(r * 32) * K + k0, adst + r * 2048);
      gload16(Bp + (size_t)(r * 32) * K + k0, bdst + r * 2048);
    }
    __syncthreads();

#pragma unroll
    for (int kb = 0; kb < 2; ++kb) {
      short8 af[4], bf[4];
      const unsigned ck = (unsigned)(kb * 32 + quad * 8) ^ xorc;
#pragma unroll
      for (int i = 0; i < 4; i++) {
        af[i] = *(const short8*)&Alds[(unsigned)(waveM * 64 + i * 16 + l16) * 64 + ck];
        bf[i] = *(const short8*)&Blds[(unsigned)(waveN * 64 + i * 16 + l16) * 64 + ck];
      }
#pragma unroll
      for (int mi = 0; mi < 4; mi++)
#pragma unroll
        for (int ni = 0; ni < 4; ni++)
          acc[mi][ni] = __builtin_amdgcn_mfma_f32_16x16x32_bf16(af[mi], bf[ni],
                                                                acc[mi][ni], 0, 0, 0);
    }
    __syncthreads();
  }

  // epilogue: C/D layout col=lane&15, row=quad*4+reg (m89/m91-verified)
  float colsum[4] = {0.0f, 0.0f, 0.0f, 0.0f};   // EPI2: per-ni column partials
#pragma unroll
  for (int mi = 0; mi < 4; mi++) {
    const int rowBase = m0 + waveM * 64 + mi * 16 + quad * 4;
#pragma unroll
    for (int ni = 0; ni < 4; ni++) {
      const int gcol = n0 + waveN * 64 + ni * 16 + l16;
#pragma unroll
      for (int r = 0; r < 4; r++) {
        const float v = acc[mi][ni][r];
        const size_t row = (size_t)(rowBase + r);
        if constexpr (EPI == 0) {
          c_out[row * (size_t)N + gcol] = v;
        } else if constexpr (EPI == 1) {
          if (gcol < DI) {
            e_bf_a[row * DI + gcol] = f2bf(v);
          } else {
            e_bf1[row * DI + (gcol - DI)] = f2bf(siluf_(v));
          }
        } else {
          const float dt = softplusf_(v + e_v2[gcol]);
          const float a  = __expf(e_v1[gcol] * dt);
          const float xc = bf2f(e_bf2[row * DI + gcol]);
          const float w  = xc * dt * a;
          e_bf_a[row * DI + gcol] = f2bf(w);
          e_bf1[row * DI + gcol] = f2bf(a);
          colsum[ni] += w;
        }
      }
    }
  }

  if constexpr (EPI == 2) {
    // fused scan_partial, barrier-free (r6-proven): shfl_xor over the quad bits
    // -> full 64-row half sum in every lane; quad==0 lanes store the half.
#pragma unroll
    for (int ni = 0; ni < 4; ++ni) {
      colsum[ni] += __shfl_xor(colsum[ni], 16);
      colsum[ni] += __shfl_xor(colsum[ni], 32);
    }
    if (quad == 0) {
      const int chunk = m0 >> 7;
#pragma unroll
      for (int ni = 0; ni < 4; ++ni) {
        const int c = n0 + waveN * 64 + ni * 16 + l16;
        e_part[((size_t)chunk * 2 + waveM) * DI + c] = colsum[ni];
      }
    }
  }
}

// ---------------- depthwise conv1d(k=3,pad=1) + bias + SiLU ----------------------
// r7: 8 channels x 4 rows per thread. 16B short8 loads (G13), row reuse:
// 6 row-loads -> 4 output rows (was 12 scalar-ish loads -> 4 rows with no reuse).
// Row groups of 4 are batch-aligned (4096 % 4 == 0), edges via l0.
__global__ void conv_silu(const u16* __restrict__ xin, const float* __restrict__ cw,
                          const float* __restrict__ cb, u16* __restrict__ xconv_bf) {
  const int idx = blockIdx.x * blockDim.x + threadIdx.x;
  const int c8  = (idx % (DI / 8)) * 8;          // 192 channel-groups
  const int g   = idx / (DI / 8);                // 4-row group index
  const int r0  = g * 4;                         // global row
  const int l0  = r0 & (L_SEQ - 1);              // within-batch row

  const size_t base = (size_t)r0 * DI + c8;
  const short8 z8 = {0, 0, 0, 0, 0, 0, 0, 0};
  short8 buf[6];
  buf[0] = (l0 > 0) ? *(const short8*)(xin + base - DI) : z8;
#pragma unroll
  for (int i = 0; i < 4; ++i)
    buf[i + 1] = *(const short8*)(xin + base + (size_t)i * DI);
  buf[5] = (l0 + 4 < L_SEQ) ? *(const short8*)(xin + base + (size_t)4 * DI) : z8;

  float w0[8], w1[8], w2[8], bb[8];
#pragma unroll
  for (int j = 0; j < 8; ++j) {
    const int c = c8 + j;
    w0[j] = cw[c * 3 + 0]; w1[j] = cw[c * 3 + 1]; w2[j] = cw[c * 3 + 2];
    bb[j] = cb[c];
  }

#pragma unroll
  for (int r = 0; r < 4; ++r) {
    short8 o;
#pragma unroll
    for (int j = 0; j < 8; ++j) {
      float v = fmaf(w0[j], bf2f((u16)buf[r][j]),
                fmaf(w1[j], bf2f((u16)buf[r + 1][j]),
                     w2[j] * bf2f((u16)buf[r + 2][j]))) + bb[j];
      o[j] = (short)f2bf(siluf_(v));
    }
    *(short8*)(xconv_bf + base + (size_t)r * DI) = o;
  }
}

// ---------------- chunked prefix scan over L (chunk=128, 32 chunks/batch) --------
#define CHUNK 128
#define NCHUNK (L_SEQ / CHUNK)   // 32

// r7: 2 channels per thread, u32 (2x bf16) loads on all four streams + packed
// store (was 4x scalar 2B loads/row). partial[] = per-64-row half sums in row
// order [chunk*2+half][DI] (written by the fused dt epilogue).
// NOTE: ybf aliases aexp (same index read-then-write per thread).
__global__ void scan_apply(const u16* __restrict__ w, const float* __restrict__ partial,
                           const u16* aexp, const u16* __restrict__ xconv,
                           const u16* __restrict__ sz, const float* __restrict__ Dp,
                           u16* ybf) {
  const int t  = blockIdx.x * 256 + threadIdx.x;   // 0..767
  const int c  = t * 2;
  const int ch = blockIdx.y;
  const int b  = blockIdx.z;

  float run0 = 0.0f, run1 = 0.0f;
  const float* pb = partial + (size_t)(b * NCHUNK) * 2 * DI;
  for (int j = 0; j < ch * 2; ++j) {
    run0 += pb[(size_t)j * DI + c];
    run1 += pb[(size_t)j * DI + c + 1];
  }
  const float dp0 = Dp[c], dp1 = Dp[c + 1];
  size_t base = ((size_t)b * L_SEQ + (size_t)ch * CHUNK) * DI + c;
  for (int i = 0; i < CHUNK; i++) {
    const size_t p = base + (size_t)i * DI;
    const uint32_t ae2 = *(const uint32_t*)(aexp + p);   // aliased: read first
    const uint32_t w2  = *(const uint32_t*)(w + p);
    const uint32_t xc2 = *(const uint32_t*)(xconv + p);
    const uint32_t sz2 = *(const uint32_t*)(sz + p);
    run0 += bf2f((u16)(w2 & 0xffffu));
    run1 += bf2f((u16)(w2 >> 16));
    float y0 = run0 * bf2f((u16)(ae2 & 0xffffu)) + bf2f((u16)(xc2 & 0xffffu)) * dp0;
    float y1 = run1 * bf2f((u16)(ae2 >> 16))     + bf2f((u16)(xc2 >> 16))     * dp1;
    y0 *= bf2f((u16)(sz2 & 0xffffu));
    y1 *= bf2f((u16)(sz2 >> 16));
    *(uint32_t*)(ybf + p) = (uint32_t)f2bf(y0) | ((uint32_t)f2bf(y1) << 16);
  }
}

// ---------------- launcher ----------------
extern "C" void kernel_launch(void* const* d_in, const int* in_sizes, int n_in,
                              void* d_out, int out_size, void* d_ws, size_t ws_size,
                              hipStream_t stream) {
  const float* x      = (const float*)d_in[0];
  const float* W_in   = (const float*)d_in[1];   // (3072,1024)
  const float* W_out  = (const float*)d_in[2];   // (1024,1536)
  const float* conv_w = (const float*)d_in[3];   // (1536,1,3)
  const float* conv_b = (const float*)d_in[4];
  const float* dt_w   = (const float*)d_in[5];   // (1536,1536)
  const float* dt_b   = (const float*)d_in[6];
  const float* Avec   = (const float*)d_in[7];
  const float* Dp     = (const float*)d_in[8];
  float* out = (float*)d_out;
  char* ws = (char*)d_ws;

  // weights -> bf16 (shared by both paths; layout prefix identical)
  u16* Win_bf  = (u16*)(ws + 0);          //  6,291,456
  u16* dtw_bf  = (u16*)(ws + 6291456);    //  4,718,592
  u16* Wout_bf = (u16*)(ws + 11010048);   //  3,145,728  -> end 14,155,776
  to_bf16<<<3072, 256, 0, stream>>>(W_in,  Win_bf,  786432);
  to_bf16<<<2304, 256, 0, stream>>>(dt_w,  dtw_bf,  589824);
  to_bf16<<<1536, 256, 0, stream>>>(W_out, Wout_bf, 393216);

  const size_t FULL_NEED = 249823232;   // full-batch layout
  if (ws_size >= FULL_NEED) {
    // ---------- full-batch path: M = 16384 ----------
    u16*   x_bf     = (u16*)  (ws + 14155776);    // 33,554,432  (16384x1024)
    u16*   xin_bf   = (u16*)  (ws + 47710208);    // 50,331,648  [w aliases]
    u16*   sz_bf    = (u16*)  (ws + 98041856);    // 50,331,648
    u16*   xconv_bf = (u16*)  (ws + 148373504);   // 50,331,648
    u16*   aexp_bf  = (u16*)  (ws + 198705152);   // 50,331,648  [y aliases]
    u16*   w_bf     = xin_bf;
    u16*   y_bf     = aexp_bf;
    // part [128 chunks][2][DI] f32 = 1,572,864 B: aliases x_bf (dead after
    // in_proj; dt writes it strictly later in stream order).
    float* part     = (float*)x_bf;

    to_bf16<<<16384, 256, 0, stream>>>(x, x_bf, 4194304);

    // in_proj GEMM (M=16384, N=3072, K=1024) + split epilogue  [r3-proven]
    gemm_bt<1><<<dim3(24, 128), 256, 0, stream>>>(x_bf, Win_bf, nullptr,
                                                  2 * DI, DIM_IN,
                                                  xin_bf, sz_bf, nullptr, nullptr, nullptr,
                                                  nullptr);
    // depthwise conv + SiLU (8ch x 4rows per thread)
    conv_silu<<<3072, 256, 0, stream>>>(xin_bf, conv_w, conv_b, xconv_bf);

    // dt GEMM (M=16384, N=1536, K=1536) + softplus/exp/w epilogue
    // + fused barrier-free per-chunk half-sums -> part
    gemm_bt<2><<<dim3(12, 128), 256, 0, stream>>>(xconv_bf, dtw_bf, nullptr,
                                                  DI, DI,
                                                  w_bf, aexp_bf, xconv_bf, Avec, dt_b,
                                                  part);

    // prefix-apply (chunk offsets computed in-block from per-chunk half-sums)
    scan_apply<<<dim3(3, NCHUNK, BATCH), 256, 0, stream>>>(w_bf, part, aexp_bf,
                                                           xconv_bf, sz_bf, Dp, y_bf);

    // out_proj GEMM (M=16384, N=1024, K=1536) -> fp32 output
    gemm_bt<0><<<dim3(8, 128), 256, 0, stream>>>(y_bf, Wout_bf, out,
                                                 DIM_IN, DI,
                                                 nullptr, nullptr, nullptr, nullptr, nullptr,
                                                 nullptr);
    return;
  }

  // ---------- per-batch fallback (73 MB), M = 4096 ----------
  const size_t WS_NEED = 73072640;
  if (ws_size < WS_NEED) return;   // diagnostic: absmax=2096 w/o crash => ws too small

  u16*   x_bf     = (u16*)  (ws + 14155776);   //  8,388,608   (4096x1024)
  u16*   xin_bf   = (u16*)  (ws + 22544384);   // 12,582,912   [w aliases]
  u16*   sz_bf    = (u16*)  (ws + 35127296);   // 12,582,912
  u16*   xconv_bf = (u16*)  (ws + 47710208);   // 12,582,912
  u16*   aexp_bf  = (u16*)  (ws + 60293120);   // 12,582,912   [y aliases]
  u16*   w_bf     = xin_bf;
  u16*   y_bf     = aexp_bf;
  // part [32 chunks][2][DI] f32 = 393,216 B: aliases x_bf (dead after in_proj
  // of the same batch; rewritten by next batch's to_bf16 only after scan_apply).
  float* part     = (float*)x_bf;

  for (int b = 0; b < BATCH; b++) {
    const float* xb   = x   + (size_t)b * L_SEQ * DIM_IN;
    float*       outb = out + (size_t)b * L_SEQ * DIM_IN;

    to_bf16<<<4096, 256, 0, stream>>>(xb, x_bf, 1048576);
    gemm_bt<1><<<dim3(24, 32), 256, 0, stream>>>(x_bf, Win_bf, nullptr,
                                                 2 * DI, DIM_IN,
                                                 xin_bf, sz_bf, nullptr, nullptr, nullptr,
                                                 nullptr);
    conv_silu<<<768, 256, 0, stream>>>(xin_bf, conv_w, conv_b, xconv_bf);
    gemm_bt<2><<<dim3(12, 32), 256, 0, stream>>>(xconv_bf, dtw_bf, nullptr,
                                                 DI, DI,
                                                 w_bf, aexp_bf, xconv_bf, Avec, dt_b,
                                                 part);
    scan_apply<<<dim3(3, NCHUNK, 1), 256, 0, stream>>>(w_bf, part, aexp_bf,
                                                       xconv_bf, sz_bf, Dp, y_bf);
    gemm_bt<0><<<dim3(8, 32), 256, 0, stream>>>(y_bf, Wout_bf, outb,
                                                DIM_IN, DI,
                                                nullptr, nullptr, nullptr, nullptr, nullptr,
                                                nullptr);
  }
}

// Round 8
// 493.694 us; speedup vs baseline: 1.2075x; 1.0123x over previous
//
#include <hip/hip_runtime.h>
#include <cstdint>
#include <cstddef>

// ---------------- problem constants ----------------
#define L_SEQ   4096
#define DIM_IN  1024
#define DI      1536
#define BATCH   4

typedef unsigned short u16;
typedef __attribute__((ext_vector_type(8))) short  short8;   // 8 bf16 = 4 VGPRs
typedef __attribute__((ext_vector_type(4))) float  f32x4;

struct __align__(8) u16x4 { u16 x, y, z, w; };

// ---------------- helpers ----------------
__device__ __forceinline__ float bf2f(u16 u) {
  union { unsigned int i; float f; } v; v.i = ((unsigned int)u) << 16; return v.f;
}
__device__ __forceinline__ u16 f2bf(float f) {
  union { float f; unsigned int i; } v; v.f = f;
  unsigned int x = v.i;
  return (u16)((x + 0x7fffu + ((x >> 16) & 1u)) >> 16);   // RNE
}
__device__ __forceinline__ float siluf_(float v) {
  return v / (1.0f + __expf(-v));
}
// __logf(1+x), x in (0,1]: abs error << bf16 rounding (r6-verified)
__device__ __forceinline__ float softplusf_(float v) {
  return fmaxf(v, 0.0f) + __logf(1.0f + __expf(-fabsf(v)));
}
__device__ __forceinline__ void gload16(const void* g, void* l) {
  __builtin_amdgcn_global_load_lds((const __attribute__((address_space(1))) void*)g,
                                   (__attribute__((address_space(3))) void*)l,
                                   16, 0, 0);
}

// ---------------- fp32 -> bf16 convert ----------------
__global__ void to_bf16(const float* __restrict__ in, u16* __restrict__ out, int n4) {
  int i = blockIdx.x * blockDim.x + threadIdx.x;
  if (i >= n4) return;
  float4 v = ((const float4*)in)[i];
  u16x4 o;
  o.x = f2bf(v.x); o.y = f2bf(v.y); o.z = f2bf(v.z); o.w = f2bf(v.w);
  ((u16x4*)out)[i] = o;
}

// r8: single ranged convert for W_in | dt_w | W_out | x (full path only).
// Weight outputs are contiguous at ws+0; x output separate. Ranges in float4s:
// [0,786432)=W_in, [786432,1376256)=dt_w, [1376256,1769472)=W_out,
// [1769472,5963776)=x. Grid 23296 x 256 covers exactly 5963776.
__global__ void to_bf16_all(const float* __restrict__ wi, const float* __restrict__ dw,
                            const float* __restrict__ wo, const float* __restrict__ xx,
                            u16* __restrict__ wdst, u16* __restrict__ xdst) {
  const int i = blockIdx.x * blockDim.x + threadIdx.x;
  float4 v;
  u16x4* dst;
  if (i < 786432)       { v = ((const float4*)wi)[i];           dst = (u16x4*)wdst + i; }
  else if (i < 1376256) { v = ((const float4*)dw)[i - 786432];  dst = (u16x4*)wdst + i; }
  else if (i < 1769472) { v = ((const float4*)wo)[i - 1376256]; dst = (u16x4*)wdst + i; }
  else                  { v = ((const float4*)xx)[i - 1769472]; dst = (u16x4*)xdst + (i - 1769472); }
  u16x4 o;
  o.x = f2bf(v.x); o.y = f2bf(v.y); o.z = f2bf(v.z); o.w = f2bf(v.w);
  *dst = o;
}

// ---------------- bf16 MFMA GEMM, C = A(MxK) * Bt(NxK)^T ----------------
// r3-proven structure: 128x128 tile, BK=64, 4 waves 2x2, per-wave 64x64,
// both-sides LDS XOR swizzle (conflicts 9.4M -> 0), bijective XCD block
// swizzle, single-buffer 2-barrier K-loop. UNTOUCHED since r6 (at the
// m97-structure ceiling ~875 TF for these shapes; 8-phase retired).
//
// EPI 0: plain fp32 C store (c_out, ld N)
// EPI 1: in_proj: col<DI -> bf16 x_inner e_bf_a; col>=DI -> silu -> bf16 e_bf1
// EPI 2: dt: dt=softplus(acc+e_v2[col]); a=exp(e_v1[col]*dt);
//        w = bf2f(e_bf2[row,col])*dt*a -> e_bf_a ; a -> e_bf1
//        + fused scan_partial as TWO per-half (64-row) sums, barrier-free.
template <int EPI>
__launch_bounds__(256, 3)
__global__ void gemm_bt(const u16* __restrict__ A, const u16* __restrict__ Bt,
                        float* __restrict__ c_out,
                        int N, int K,
                        u16* __restrict__ e_bf_a,
                        u16* __restrict__ e_bf1,
                        const u16* __restrict__ e_bf2,
                        const float* __restrict__ e_v1,
                        const float* __restrict__ e_v2,
                        float* __restrict__ e_part) {
  __shared__ u16 Alds[128 * 64];   // 16 KB
  __shared__ u16 Blds[128 * 64];   // 16 KB

  const int tid  = threadIdx.x;
  const int wave = tid >> 6;
  const int lane = tid & 63;
  const int quad = lane >> 4;
  const int l16  = lane & 15;

  // bijective XCD-aware block swizzle (nwg % 8 == 0 for every grid used here)
  const int nwg  = (int)(gridDim.x * gridDim.y);
  const int orig = (int)(blockIdx.y * gridDim.x + blockIdx.x);
  const int swz  = (orig & 7) * (nwg >> 3) + (orig >> 3);
  const int bx   = swz % (int)gridDim.x;
  const int by   = swz / (int)gridDim.x;
  const int m0 = by * 128;
  const int n0 = bx * 128;

  const int waveM = wave & 1;      // 2x2 wave grid
  const int waveN = wave >> 1;

  // staging: tile = 128 rows x 128 B; thread covers 4 x 16B chunks per matrix:
  // row = r*32 + (tid>>3), seg = tid&7, source col pre-swizzled by (row&7) so
  // the linear global_load_lds DMA lands the swizzled layout.
  const int srow = tid >> 3;                       // 0..31
  const int scol = ((tid & 7) ^ (srow & 7)) * 8;   // pre-swizzled source col (elems)
  const u16* Ap = A  + (size_t)(m0 + srow) * K + scol;
  const u16* Bp = Bt + (size_t)(n0 + srow) * K + scol;
  u16* adst = &Alds[tid * 8];
  u16* bdst = &Blds[tid * 8];

  const unsigned xorc = (unsigned)(l16 & 7) << 3;  // read-side involution (elems)

  f32x4 acc[4][4] = {};

  for (int k0 = 0; k0 < K; k0 += 64) {
#pragma unroll
    for (int r = 0; r < 4; ++r) {
      gload16(Ap + (size_t)(r * 32) * K + k0, adst + r * 2048);
      gload16(Bp + (size_t)(r * 32) * K + k0, bdst + r * 2048);
    }
    __syncthreads();

#pragma unroll
    for (int kb = 0; kb < 2; ++kb) {
      short8 af[4], bf[4];
      const unsigned ck = (unsigned)(kb * 32 + quad * 8) ^ xorc;
#pragma unroll
      for (int i = 0; i < 4; i++) {
        af[i] = *(const short8*)&Alds[(unsigned)(waveM * 64 + i * 16 + l16) * 64 + ck];
        bf[i] = *(const short8*)&Blds[(unsigned)(waveN * 64 + i * 16 + l16) * 64 + ck];
      }
#pragma unroll
      for (int mi = 0; mi < 4; mi++)
#pragma unroll
        for (int ni = 0; ni < 4; ni++)
          acc[mi][ni] = __builtin_amdgcn_mfma_f32_16x16x32_bf16(af[mi], bf[ni],
                                                                acc[mi][ni], 0, 0, 0);
    }
    __syncthreads();
  }

  // epilogue: C/D layout col=lane&15, row=quad*4+reg (m89/m91-verified)
  float colsum[4] = {0.0f, 0.0f, 0.0f, 0.0f};   // EPI2: per-ni column partials
#pragma unroll
  for (int mi = 0; mi < 4; mi++) {
    const int rowBase = m0 + waveM * 64 + mi * 16 + quad * 4;
#pragma unroll
    for (int ni = 0; ni < 4; ni++) {
      const int gcol = n0 + waveN * 64 + ni * 16 + l16;
#pragma unroll
      for (int r = 0; r < 4; r++) {
        const float v = acc[mi][ni][r];
        const size_t row = (size_t)(rowBase + r);
        if constexpr (EPI == 0) {
          c_out[row * (size_t)N + gcol] = v;
        } else if constexpr (EPI == 1) {
          if (gcol < DI) {
            e_bf_a[row * DI + gcol] = f2bf(v);
          } else {
            e_bf1[row * DI + (gcol - DI)] = f2bf(siluf_(v));
          }
        } else {
          const float dt = softplusf_(v + e_v2[gcol]);
          const float a  = __expf(e_v1[gcol] * dt);
          const float xc = bf2f(e_bf2[row * DI + gcol]);
          const float w  = xc * dt * a;
          e_bf_a[row * DI + gcol] = f2bf(w);
          e_bf1[row * DI + gcol] = f2bf(a);
          colsum[ni] += w;
        }
      }
    }
  }

  if constexpr (EPI == 2) {
    // fused scan_partial, barrier-free (r6-proven): shfl_xor over the quad bits
    // -> full 64-row half sum in every lane; quad==0 lanes store the half.
#pragma unroll
    for (int ni = 0; ni < 4; ++ni) {
      colsum[ni] += __shfl_xor(colsum[ni], 16);
      colsum[ni] += __shfl_xor(colsum[ni], 32);
    }
    if (quad == 0) {
      const int chunk = m0 >> 7;
#pragma unroll
      for (int ni = 0; ni < 4; ++ni) {
        const int c = n0 + waveN * 64 + ni * 16 + l16;
        e_part[((size_t)chunk * 2 + waveM) * DI + c] = colsum[ni];
      }
    }
  }
}

// ---------------- depthwise conv1d(k=3,pad=1) + bias + SiLU ----------------------
// r8: 8 channels x 8 rows per thread. 16B short8 loads, 10 row-loads -> 8 output
// rows (read amplification 1.25x, was 1.5x). Groups of 8 rows are batch-aligned
// (4096 % 8 == 0); edges via l0.
__global__ void conv_silu(const u16* __restrict__ xin, const float* __restrict__ cw,
                          const float* __restrict__ cb, u16* __restrict__ xconv_bf) {
  const int idx = blockIdx.x * blockDim.x + threadIdx.x;
  const int c8  = (idx % (DI / 8)) * 8;          // 192 channel-groups
  const int g   = idx / (DI / 8);                // 8-row group index
  const int r0  = g * 8;                         // global row
  const int l0  = r0 & (L_SEQ - 1);              // within-batch row

  const size_t base = (size_t)r0 * DI + c8;
  const short8 z8 = {0, 0, 0, 0, 0, 0, 0, 0};
  short8 buf[10];
  buf[0] = (l0 > 0) ? *(const short8*)(xin + base - DI) : z8;
#pragma unroll
  for (int i = 0; i < 8; ++i)
    buf[i + 1] = *(const short8*)(xin + base + (size_t)i * DI);
  buf[9] = (l0 + 8 < L_SEQ) ? *(const short8*)(xin + base + (size_t)8 * DI) : z8;

  float w0[8], w1[8], w2[8], bb[8];
#pragma unroll
  for (int j = 0; j < 8; ++j) {
    const int c = c8 + j;
    w0[j] = cw[c * 3 + 0]; w1[j] = cw[c * 3 + 1]; w2[j] = cw[c * 3 + 2];
    bb[j] = cb[c];
  }

#pragma unroll
  for (int r = 0; r < 8; ++r) {
    short8 o;
#pragma unroll
    for (int j = 0; j < 8; ++j) {
      float v = fmaf(w0[j], bf2f((u16)buf[r][j]),
                fmaf(w1[j], bf2f((u16)buf[r + 1][j]),
                     w2[j] * bf2f((u16)buf[r + 2][j]))) + bb[j];
      o[j] = (short)f2bf(siluf_(v));
    }
    *(short8*)(xconv_bf + base + (size_t)r * DI) = o;
  }
}

// ---------------- chunked prefix scan over L --------------------------------------
// r8: scan chunk = 64 rows (== one partial half-entry) -> grid doubles to
// (3,64,B) = 768 blocks, 12 waves/CU (was 6) for the latency-bound main loop.
// Prefix cost unchanged (<=63 entry reads either way).
#define SCHUNK 64
#define NSCH (L_SEQ / SCHUNK)   // 64 entries of 64 rows per batch

// partial[] = per-64-row half sums in row order (written by dt epilogue as
// [chunk128*2 + half][DI] == [entry64][DI]). 2 channels/thread, u32 loads.
// NOTE: ybf aliases aexp (same index read-then-write per thread).
__global__ void scan_apply(const u16* __restrict__ w, const float* __restrict__ partial,
                           const u16* aexp, const u16* __restrict__ xconv,
                           const u16* __restrict__ sz, const float* __restrict__ Dp,
                           u16* ybf) {
  const int t  = blockIdx.x * 256 + threadIdx.x;   // 0..767
  const int c  = t * 2;
  const int ch = blockIdx.y;                       // 0..63
  const int b  = blockIdx.z;

  float run0 = 0.0f, run1 = 0.0f;
  const float* pb = partial + (size_t)(b * NSCH) * DI;
  for (int j = 0; j < ch; ++j) {
    run0 += pb[(size_t)j * DI + c];
    run1 += pb[(size_t)j * DI + c + 1];
  }
  const float dp0 = Dp[c], dp1 = Dp[c + 1];
  size_t base = ((size_t)b * L_SEQ + (size_t)ch * SCHUNK) * DI + c;
  for (int i = 0; i < SCHUNK; i++) {
    const size_t p = base + (size_t)i * DI;
    const uint32_t ae2 = *(const uint32_t*)(aexp + p);   // aliased: read first
    const uint32_t w2  = *(const uint32_t*)(w + p);
    const uint32_t xc2 = *(const uint32_t*)(xconv + p);
    const uint32_t sz2 = *(const uint32_t*)(sz + p);
    run0 += bf2f((u16)(w2 & 0xffffu));
    run1 += bf2f((u16)(w2 >> 16));
    float y0 = run0 * bf2f((u16)(ae2 & 0xffffu)) + bf2f((u16)(xc2 & 0xffffu)) * dp0;
    float y1 = run1 * bf2f((u16)(ae2 >> 16))     + bf2f((u16)(xc2 >> 16))     * dp1;
    y0 *= bf2f((u16)(sz2 & 0xffffu));
    y1 *= bf2f((u16)(sz2 >> 16));
    *(uint32_t*)(ybf + p) = (uint32_t)f2bf(y0) | ((uint32_t)f2bf(y1) << 16);
  }
}

// ---------------- launcher ----------------
extern "C" void kernel_launch(void* const* d_in, const int* in_sizes, int n_in,
                              void* d_out, int out_size, void* d_ws, size_t ws_size,
                              hipStream_t stream) {
  const float* x      = (const float*)d_in[0];
  const float* W_in   = (const float*)d_in[1];   // (3072,1024)
  const float* W_out  = (const float*)d_in[2];   // (1024,1536)
  const float* conv_w = (const float*)d_in[3];   // (1536,1,3)
  const float* conv_b = (const float*)d_in[4];
  const float* dt_w   = (const float*)d_in[5];   // (1536,1536)
  const float* dt_b   = (const float*)d_in[6];
  const float* Avec   = (const float*)d_in[7];
  const float* Dp     = (const float*)d_in[8];
  float* out = (float*)d_out;
  char* ws = (char*)d_ws;

  // weight bf16 layout (contiguous from ws+0; both paths identical)
  u16* Win_bf  = (u16*)(ws + 0);          //  6,291,456
  u16* dtw_bf  = (u16*)(ws + 6291456);    //  4,718,592
  u16* Wout_bf = (u16*)(ws + 11010048);   //  3,145,728  -> end 14,155,776

  const size_t FULL_NEED = 249823232;   // full-batch layout
  if (ws_size >= FULL_NEED) {
    // ---------- full-batch path: M = 16384 ----------
    u16*   x_bf     = (u16*)  (ws + 14155776);    // 33,554,432  (16384x1024)
    u16*   xin_bf   = (u16*)  (ws + 47710208);    // 50,331,648  [w aliases]
    u16*   sz_bf    = (u16*)  (ws + 98041856);    // 50,331,648
    u16*   xconv_bf = (u16*)  (ws + 148373504);   // 50,331,648
    u16*   aexp_bf  = (u16*)  (ws + 198705152);   // 50,331,648  [y aliases]
    u16*   w_bf     = xin_bf;
    u16*   y_bf     = aexp_bf;
    // part [256 entries][DI] f32 = 1,572,864 B: aliases x_bf (dead after
    // in_proj; dt writes it strictly later in stream order).
    float* part     = (float*)x_bf;

    // single ranged convert: W_in | dt_w | W_out | x  (3 launches saved)
    to_bf16_all<<<23296, 256, 0, stream>>>(W_in, dt_w, W_out, x,
                                           (u16*)ws, x_bf);

    // in_proj GEMM (M=16384, N=3072, K=1024) + split epilogue  [r3-proven]
    gemm_bt<1><<<dim3(24, 128), 256, 0, stream>>>(x_bf, Win_bf, nullptr,
                                                  2 * DI, DIM_IN,
                                                  xin_bf, sz_bf, nullptr, nullptr, nullptr,
                                                  nullptr);
    // depthwise conv + SiLU (8ch x 8rows per thread)
    conv_silu<<<1536, 256, 0, stream>>>(xin_bf, conv_w, conv_b, xconv_bf);

    // dt GEMM (M=16384, N=1536, K=1536) + softplus/exp/w epilogue
    // + fused barrier-free per-64-row half-sums -> part
    gemm_bt<2><<<dim3(12, 128), 256, 0, stream>>>(xconv_bf, dtw_bf, nullptr,
                                                  DI, DI,
                                                  w_bf, aexp_bf, xconv_bf, Avec, dt_b,
                                                  part);

    // prefix-apply over 64-row chunks (offsets computed in-block)
    scan_apply<<<dim3(3, NSCH, BATCH), 256, 0, stream>>>(w_bf, part, aexp_bf,
                                                         xconv_bf, sz_bf, Dp, y_bf);

    // out_proj GEMM (M=16384, N=1024, K=1536) -> fp32 output
    gemm_bt<0><<<dim3(8, 128), 256, 0, stream>>>(y_bf, Wout_bf, out,
                                                 DIM_IN, DI,
                                                 nullptr, nullptr, nullptr, nullptr, nullptr,
                                                 nullptr);
    return;
  }

  // ---------- per-batch fallback (73 MB), M = 4096 ----------
  const size_t WS_NEED = 73072640;
  if (ws_size < WS_NEED) return;   // diagnostic: absmax=2096 w/o crash => ws too small

  to_bf16<<<3072, 256, 0, stream>>>(W_in,  Win_bf,  786432);
  to_bf16<<<2304, 256, 0, stream>>>(dt_w,  dtw_bf,  589824);
  to_bf16<<<1536, 256, 0, stream>>>(W_out, Wout_bf, 393216);

  u16*   x_bf     = (u16*)  (ws + 14155776);   //  8,388,608   (4096x1024)
  u16*   xin_bf   = (u16*)  (ws + 22544384);   // 12,582,912   [w aliases]
  u16*   sz_bf    = (u16*)  (ws + 35127296);   // 12,582,912
  u16*   xconv_bf = (u16*)  (ws + 47710208);   // 12,582,912
  u16*   aexp_bf  = (u16*)  (ws + 60293120);   // 12,582,912   [y aliases]
  u16*   w_bf     = xin_bf;
  u16*   y_bf     = aexp_bf;
  // part [64 entries][DI] f32 = 393,216 B: aliases x_bf (dead after in_proj
  // of the same batch; rewritten by next batch's to_bf16 only after scan_apply).
  float* part     = (float*)x_bf;

  for (int b = 0; b < BATCH; b++) {
    const float* xb   = x   + (size_t)b * L_SEQ * DIM_IN;
    float*       outb = out + (size_t)b * L_SEQ * DIM_IN;

    to_bf16<<<4096, 256, 0, stream>>>(xb, x_bf, 1048576);
    gemm_bt<1><<<dim3(24, 32), 256, 0, stream>>>(x_bf, Win_bf, nullptr,
                                                 2 * DI, DIM_IN,
                                                 xin_bf, sz_bf, nullptr, nullptr, nullptr,
                                                 nullptr);
    conv_silu<<<384, 256, 0, stream>>>(xin_bf, conv_w, conv_b, xconv_bf);
    gemm_bt<2><<<dim3(12, 32), 256, 0, stream>>>(xconv_bf, dtw_bf, nullptr,
                                                 DI, DI,
                                                 w_bf, aexp_bf, xconv_bf, Avec, dt_b,
                                                 part);
    scan_apply<<<dim3(3, NSCH, 1), 256, 0, stream>>>(w_bf, part, aexp_bf,
                                                     xconv_bf, sz_bf, Dp, y_bf);
    gemm_bt<0><<<dim3(8, 32), 256, 0, stream>>>(y_bf, Wout_bf, outb,
                                                DIM_IN, DI,
                                                nullptr, nullptr, nullptr, nullptr, nullptr,
                                                nullptr);
  }
}